// Round 1
// baseline (1472.596 us; speedup 1.0000x reference)
//
#include <hip/hip_runtime.h>
#include <math.h>

// SDN room acoustics: B=4 independent sims, each run by one 64-lane wave.
// Lanes 0..29: delay lines (b2 rows, scatter rows). Lanes 30..35: mic FIR rows (b3).
// Lanes 36..63: dummy (zero coeffs). All delay rows are lane-private in LDS;
// cross-lane mixing via shuffles only -> no __syncthreads in the main loop.

#define NN    6
#define NLn   30
#define FIRN  7
#define TCAP  4000
#define LCAP  272               // >= max delay (<=261) + FIR + 1
#define ROWSZ (LCAP + FIRN)     // 7-slot mirrored prefix for wrap-free FIR reads

__global__ __launch_bounds__(64)
void sdn_kernel(const float* __restrict__ x, const float* __restrict__ srcp,
                const float* __restrict__ micp, const float* __restrict__ jf,
                const float* __restrict__ jv, const float* __restrict__ pw,
                float* __restrict__ out, int T)
{
    const int b = blockIdx.x;
    const int l = threadIdx.x;

    __shared__ float  b2s[NLn][ROWSZ];
    __shared__ float  b3s[NN][ROWSZ];
    __shared__ float  dum[ROWSZ];
    __shared__ float  xl[TCAP];
    __shared__ double nds[NN][3];

    for (int i = l; i < NLn * ROWSZ; i += 64) (&b2s[0][0])[i] = 0.f;
    for (int i = l; i < NN * ROWSZ;  i += 64) (&b3s[0][0])[i] = 0.f;
    for (int i = l; i < ROWSZ;       i += 64) dum[i] = 0.f;
    for (int i = l; i < T;           i += 64) xl[i] = x[i];

    const double room[3] = {4.0, 3.0, 2.5};
    double src[3] = {srcp[0], srcp[1], srcp[2]};
    double mic[3] = {micp[3*b+0], micp[3*b+1], micp[3*b+2]};

    // node j: axis a=j/2, wall w = (j&1)? room[a] : 0  -- double precision, matches numpy
    if (l < NN) {
        int a = l >> 1;
        double w = (l & 1) ? room[a] : 0.0;
        double sa = (a == 0) ? src[0] : ((a == 1) ? src[1] : src[2]);
        double ma = (a == 0) ? mic[0] : ((a == 1) ? mic[1] : mic[2]);
        double ia = 2.0 * w - sa;
        double img0 = src[0], img1 = src[1], img2 = src[2];
        if (a == 0) img0 = ia; else if (a == 1) img1 = ia; else img2 = ia;
        double t = (w - ia) / (ma - ia);
        nds[l][0] = img0 + t * (mic[0] - img0);
        nds[l][1] = img1 + t * (mic[1] - img1);
        nds[l][2] = img2 + t * (mic[2] - img2);
    }
    __syncthreads();

    const double G = 343.0 / 16000.0;
    // node this lane is associated with
    int n = (l < NLn) ? (l / 5) : ((l < NLn + NN) ? (l - NLn) : 0);

    double dx = nds[n][0] - src[0], dy = nds[n][1] - src[1], dz = nds[n][2] - src[2];
    double dsn = sqrt(dx*dx + dy*dy + dz*dz);
    dx = nds[n][0] - mic[0]; dy = nds[n][1] - mic[1]; dz = nds[n][2] - mic[2];
    double dnm = sqrt(dx*dx + dy*dy + dz*dz);
    dx = mic[0] - src[0]; dy = mic[1] - src[1]; dz = mic[2] - src[2];
    double dsm = sqrt(dx*dx + dy*dy + dz*dz);

    int   Dsn  = (int)rint(dsn / G);
    int   Dsm  = (int)rint(dsm / G);
    float srcg = (float)(0.5 * G / dsn);
    float micg = (float)(1.0 / (1.0 + dnm / dsn));
    float dirg = (float)(1.0 / dsm);

    // FIR row delay for this lane
    int Dl;
    if (l < NLn) {
        int i5 = l / 5, mm = l % 5;
        int m = mm + (mm >= i5 ? 1 : 0);            // PAIRS[(i,m), m != i]
        double ax = nds[i5][0] - nds[m][0];
        double ay = nds[i5][1] - nds[m][1];
        double az = nds[i5][2] - nds[m][2];
        Dl = (int)rint(sqrt(ax*ax + ay*ay + az*az) / G);
    } else if (l < NLn + NN) {
        Dl = (int)rint(dnm / G);
    } else {
        Dl = 64;                                     // dummy lanes
    }

    // scatter matrix row: S[n][ir][j] = 2*v_ir*v_j/uu - delta
    int ir = l % 5;
    float v0 = jv[n*5+0], v1 = jv[n*5+1], v2 = jv[n*5+2], v3 = jv[n*5+3], v4 = jv[n*5+4];
    float uu = v0*v0 + v1*v1 + v2*v2 + v3*v3 + v4*v4;
    float vi = jv[n*5+ir];
    float s0 = 2.0f*(vi*v0)/uu - (ir==0 ? 1.f : 0.f);
    float s1 = 2.0f*(vi*v1)/uu - (ir==1 ? 1.f : 0.f);
    float s2 = 2.0f*(vi*v2)/uu - (ir==2 ? 1.f : 0.f);
    float s3 = 2.0f*(vi*v3)/uu - (ir==3 ? 1.f : 0.f);
    float s4 = 2.0f*(vi*v4)/uu - (ir==4 ? 1.f : 0.f);

    // FIR coefficients, reversed: c[j] applies to sample at delay D + j
    float c[FIRN+1];
    #pragma unroll
    for (int j = 0; j <= FIRN; ++j)
        c[j] = (l < NLn + NN) ? jf[n*(FIRN+1) + (FIRN - j)] : 0.f;

    float pwl   = (l < NLn) ? pw[l] : 0.f;
    int   perml = (6*(l+1) - (l % 6) - 1) % NLn;
    int   gb    = n * 5;                             // gather base within node group

    float* rowp = (l < NLn) ? &b2s[l][FIRN]
                : ((l < NLn + NN) ? &b3s[l - NLn][FIRN] : &dum[FIRN]);

    __syncthreads();

    int   wp = 0;                // write slot = k % LCAP
    int   rp = LCAP - Dl;        // read slot  = (k - Dl) % LCAP
    float pp = 0.f;              // incoming wave variable (lanes 0..29)

    #pragma unroll 4
    for (int k = 0; k < T; ++k) {
        // source injection (pure delay of x)
        int   xi = k - Dsn;
        float xv = xl[xi < 0 ? 0 : xi];
        xv = (xi < 0) ? 0.f : xv;
        float p = pp + srcg * xv;

        // pm = S_row . pp(node group)
        float q0 = __shfl(p, gb + 0);
        float q1 = __shfl(p, gb + 1);
        float q2 = __shfl(p, gb + 2);
        float q3 = __shfl(p, gb + 3);
        float q4 = __shfl(p, gb + 4);
        float pm = s0*q0 + s1*q1 + s2*q2 + s3*q3 + s4*q4;

        // node pressure = sum_j pm[n,j]*pw3[n,j]  (needed on mic lanes 30..35)
        float tt = pm * pwl;
        float u0 = __shfl(tt, gb + 0);
        float u1 = __shfl(tt, gb + 1);
        float u2 = __shfl(tt, gb + 2);
        float u3 = __shfl(tt, gb + 3);
        float u4 = __shfl(tt, gb + 4);
        float pnode = ((u0 + u1) + (u2 + u3)) + u4;

        // write current sample into my circular row (+ mirror prefix for wrap-free reads)
        float wv = (l < NLn) ? pm : micg * pnode;
        if (l < NLn + NN) {
            rowp[wp] = wv;
            if (wp >= LCAP - FIRN) rowp[wp - LCAP] = wv;
        }

        // 8-tap FIR on my row at my delay
        float acc = 0.f;
        #pragma unroll
        for (int j = 0; j <= FIRN; ++j)
            acc = fmaf(c[j], rowp[rp - j], acc);

        // line permutation -> next pp (lanes 0..29)
        float ppn = __shfl(acc, perml);

        // mic sum: lanes 30..35 hold per-node contributions, 36..37 are zero
        float ssum = acc;
        ssum += __shfl_down(ssum, 1);
        ssum += __shfl_down(ssum, 2);
        ssum += __shfl_down(ssum, 4);

        // direct path
        int   xdi = k - Dsm;
        float xd  = xl[xdi < 0 ? 0 : xdi];
        float yd  = (xdi < 0) ? 0.f : dirg * xd;

        if (l == NLn) out[b * T + k] = ssum + yd;

        pp = ppn;
        wp = (wp + 1 == LCAP) ? 0 : wp + 1;
        rp = (rp + 1 == LCAP) ? 0 : rp + 1;
    }
}

extern "C" void kernel_launch(void* const* d_in, const int* in_sizes, int n_in,
                              void* d_out, int out_size, void* d_ws, size_t ws_size,
                              hipStream_t stream)
{
    const float* x    = (const float*)d_in[0];
    const float* srcp = (const float*)d_in[1];
    const float* micp = (const float*)d_in[2];
    const float* jf   = (const float*)d_in[3];
    const float* jv   = (const float*)d_in[4];
    const float* pw   = (const float*)d_in[5];
    float* out = (float*)d_out;

    int T  = in_sizes[0];
    int Bc = in_sizes[2] / 3;

    sdn_kernel<<<Bc, 64, 0, stream>>>(x, srcp, micp, jf, jv, pw, out, T);
}

// Round 2
// 992.014 us; speedup vs baseline: 1.4845x; 1.4845x over previous
//
#include <hip/hip_runtime.h>
#include <math.h>

// SDN room acoustics: B=4 independent sims, one 64-lane wave each.
// Lanes 0..29: scattering delay lines (b2 rows). Lanes 30..35: mic FIR rows (b3).
// Lane 36: carries the direct src->mic path. Lanes 37..63: idle (zero coeffs).
//
// Per-step math (Householder form of the scatter matrix S = 2vv^T/uu - I):
//   p_j   = acc_prev[PERM[gb+j]] + inj          (perm fused into the gather)
//   s     = 2 (v . p) / uu
//   pm_i  = s*v_i - p_i                         (line lanes)
//   pnode = s*(v.pw) - (pw . p)                 (mic lanes)
// FIR is in transposed form: 1 LDS tap read + 7 register z-states per lane.

#define NN    6
#define NLn   30
#define FIRN  7
#define TCAP  4000
#define LCAP  273                // > max delay (<=261), odd => conflict-free row stride
#define PADX  264                // zero prefix so x[k-D] needs no bounds check
#define NROW  37                 // 30 lines + 6 mic + 1 dummy

__global__ __launch_bounds__(64)
void sdn_kernel(const float* __restrict__ x, const float* __restrict__ srcp,
                const float* __restrict__ micp, const float* __restrict__ jf,
                const float* __restrict__ jv, const float* __restrict__ pw,
                float* __restrict__ out, int T)
{
    const int b = blockIdx.x;
    const int l = threadIdx.x;

    __shared__ float  rows[NROW][LCAP];
    __shared__ float  xl[PADX + TCAP];
    __shared__ double nds[NN][3];

    for (int i = l; i < NROW * LCAP; i += 64) (&rows[0][0])[i] = 0.f;
    for (int i = l; i < PADX;        i += 64) xl[i] = 0.f;
    for (int i = l; i < T;           i += 64) xl[PADX + i] = x[i];

    const double room[3] = {4.0, 3.0, 2.5};
    double src[3] = {srcp[0], srcp[1], srcp[2]};
    double mic[3] = {micp[3*b+0], micp[3*b+1], micp[3*b+2]};

    // node j: axis a=j/2, wall w=(j&1)?room[a]:0 -- double precision, matches numpy
    if (l < NN) {
        int a = l >> 1;
        double w = (l & 1) ? room[a] : 0.0;
        double sa = (a == 0) ? src[0] : ((a == 1) ? src[1] : src[2]);
        double ma = (a == 0) ? mic[0] : ((a == 1) ? mic[1] : mic[2]);
        double ia = 2.0 * w - sa;
        double img0 = src[0], img1 = src[1], img2 = src[2];
        if (a == 0) img0 = ia; else if (a == 1) img1 = ia; else img2 = ia;
        double t = (w - ia) / (ma - ia);
        nds[l][0] = img0 + t * (mic[0] - img0);
        nds[l][1] = img1 + t * (mic[1] - img1);
        nds[l][2] = img2 + t * (mic[2] - img2);
    }
    __syncthreads();

    const double G = 343.0 / 16000.0;
    const int n = (l < NLn) ? (l / 5) : ((l < NLn + NN) ? (l - NLn) : 0);

    double dx = nds[n][0] - src[0], dy = nds[n][1] - src[1], dz = nds[n][2] - src[2];
    double dsn = sqrt(dx*dx + dy*dy + dz*dz);
    dx = nds[n][0] - mic[0]; dy = nds[n][1] - mic[1]; dz = nds[n][2] - mic[2];
    double dnm = sqrt(dx*dx + dy*dy + dz*dz);
    dx = mic[0] - src[0]; dy = mic[1] - src[1]; dz = mic[2] - src[2];
    double dsm = sqrt(dx*dx + dy*dy + dz*dz);

    const int   Dsn  = (int)rint(dsn / G);
    const int   Dsm  = (int)rint(dsm / G);
    const float srcg = (float)(0.5 * G / dsn);
    const float micg = (float)(1.0 / (1.0 + dnm / dsn));
    const float dirg = (float)(1.0 / dsm);

    // ring-read delay for this lane's row
    int Dl;
    if (l < NLn) {
        int i5 = l / 5, mm = l % 5;
        int m = mm + (mm >= i5 ? 1 : 0);            // PAIRS[(i,m)], m != i
        double ax = nds[i5][0] - nds[m][0];
        double ay = nds[i5][1] - nds[m][1];
        double az = nds[i5][2] - nds[m][2];
        Dl = (int)rint(sqrt(ax*ax + ay*ay + az*az) / G);
    } else if (l < NLn + NN) {
        Dl = (int)rint(dnm / G);
    } else {
        Dl = 64;                                    // dummy row, reads zeros
    }

    // injection gain + x-offset; lane 36 carries the direct path
    float srcgl; int xoff;
    if (l < NLn + NN)       { srcgl = srcg; xoff = PADX - Dsn; }
    else if (l == NLn + NN) { srcgl = dirg; xoff = PADX - Dsm; }
    else                    { srcgl = 0.f;  xoff = PADX; }

    // Householder vectors
    const bool active = (l < NLn + NN);
    float v0 = active ? jv[n*5+0] : 0.f, v1 = active ? jv[n*5+1] : 0.f;
    float v2 = active ? jv[n*5+2] : 0.f, v3 = active ? jv[n*5+3] : 0.f;
    float v4 = active ? jv[n*5+4] : 0.f;
    float uu = jv[n*5+0]*jv[n*5+0] + jv[n*5+1]*jv[n*5+1] + jv[n*5+2]*jv[n*5+2]
             + jv[n*5+3]*jv[n*5+3] + jv[n*5+4]*jv[n*5+4];
    const float c2u = 2.0f / uu;
    const float SV  = v0 + v1 + v2 + v3 + v4;

    // per-lane write-value coefficients: wv = s*Wa - (sum w_j g_j + injv*wsv)
    float w0, w1, w2, w3, w4, wsv, Wa;
    if (l < NLn) {
        int ir = l % 5;
        w0 = (ir==0); w1 = (ir==1); w2 = (ir==2); w3 = (ir==3); w4 = (ir==4);
        wsv = 1.f;
        Wa = (ir==0)?v0:((ir==1)?v1:((ir==2)?v2:((ir==3)?v3:v4)));
    } else if (l < NLn + NN) {
        float q0 = pw[n*5+0], q1 = pw[n*5+1], q2 = pw[n*5+2], q3 = pw[n*5+3], q4 = pw[n*5+4];
        w0 = micg*q0; w1 = micg*q1; w2 = micg*q2; w3 = micg*q3; w4 = micg*q4;
        wsv = micg * (q0+q1+q2+q3+q4);
        Wa  = micg * (v0*q0 + v1*q1 + v2*q2 + v3*q3 + v4*q4);
    } else {
        w0=w1=w2=w3=w4=0.f; wsv=0.f; Wa=0.f;
    }

    // FIR coefficients, reversed: c[t] applies to u(k-t), u(k)=row[k-Dl]
    float c0,c1,c2,c3,c4,c5,c6,c7;
    {
        const float* f = jf + n*(FIRN+1);
        c0 = active ? f[7] : 0.f; c1 = active ? f[6] : 0.f;
        c2 = active ? f[5] : 0.f; c3 = active ? f[4] : 0.f;
        c4 = active ? f[3] : 0.f; c5 = active ? f[2] : 0.f;
        c6 = active ? f[1] : 0.f; c7 = active ? f[0] : 0.f;
    }

    // gather lane indices: p_j = accPrev[PERM[gb+j]]
    const int gb = n * 5;
    int p0=0,p1=0,p2=0,p3=0,p4=0;
    if (active) {
        #define PERMF(i) ((6*((i)+1) - ((i)%6) - 1) % NLn)
        p0 = PERMF(gb+0); p1 = PERMF(gb+1); p2 = PERMF(gb+2);
        p3 = PERMF(gb+3); p4 = PERMF(gb+4);
        #undef PERMF
    }

    float* rbase = rows[l < NROW-1 ? l : NROW-1];
    float* rend  = rbase + LCAP;
    float* up    = rbase + (LCAP - Dl);
    float* wap   = rbase;
    const float* xp = xl + xoff;
    float* outp  = out + b * T;

    __syncthreads();

    float z1=0.f,z2=0.f,z3=0.f,z4=0.f,z5=0.f,z6=0.f,z7=0.f;
    float accPrev = 0.f;

    #pragma unroll 8
    for (int k = 0; k < T; ++k) {
        float xr   = xp[k];
        float u    = *up;
        up++; if (up == rend) up = rbase;
        float injv = srcgl * xr;

        // transposed FIR (acc depends only on >=~29-step-old data -> pipelines)
        float acc = fmaf(c0, u, z1);
        z1 = fmaf(c1, u, z2); z2 = fmaf(c2, u, z3); z3 = fmaf(c3, u, z4);
        z4 = fmaf(c4, u, z5); z5 = fmaf(c5, u, z6); z6 = fmaf(c6, u, z7);
        z7 = c7 * u;
        if (l == NLn + NN) acc = injv;      // lane 36: direct path rides the mic sum

        // one gather level: p_j = accPrev[perm] (+ group-uniform injection folded in)
        float g0 = __shfl(accPrev, p0);
        float g1 = __shfl(accPrev, p1);
        float g2 = __shfl(accPrev, p2);
        float g3 = __shfl(accPrev, p3);
        float g4 = __shfl(accPrev, p4);

        float vdot = fmaf(v0,g0, fmaf(v1,g1, fmaf(v2,g2, fmaf(v3,g3, fmaf(v4,g4, injv*SV)))));
        float s    = vdot * c2u;
        float wdot = fmaf(w0,g0, fmaf(w1,g1, fmaf(w2,g2, fmaf(w3,g3, fmaf(w4,g4, injv*wsv)))));
        float wv   = fmaf(s, Wa, -wdot);

        if (l < NLn + NN) *wap = wv;
        wap++; if (wap == rend) wap = rbase;

        // mic sum: lanes 30..35 FIR outs + lane 36 direct, lane 37 = 0
        float ss = acc;
        ss += __shfl_down(ss, 1);
        ss += __shfl_down(ss, 2);
        ss += __shfl_down(ss, 4);
        if (l == NLn) outp[k] = ss;

        accPrev = acc;
    }
}

extern "C" void kernel_launch(void* const* d_in, const int* in_sizes, int n_in,
                              void* d_out, int out_size, void* d_ws, size_t ws_size,
                              hipStream_t stream)
{
    const float* x    = (const float*)d_in[0];
    const float* srcp = (const float*)d_in[1];
    const float* micp = (const float*)d_in[2];
    const float* jf   = (const float*)d_in[3];
    const float* jv   = (const float*)d_in[4];
    const float* pw   = (const float*)d_in[5];
    float* out = (float*)d_out;

    int T  = in_sizes[0];
    if (T > TCAP) T = TCAP;
    int Bc = in_sizes[2] / 3;

    sdn_kernel<<<Bc, 64, 0, stream>>>(x, srcp, micp, jf, jv, pw, out, T);
}

// Round 3
// 798.306 us; speedup vs baseline: 1.8447x; 1.2426x over previous
//
#include <hip/hip_runtime.h>
#include <math.h>

// SDN room acoustics: B=4 independent sims, one 64-lane wave each.
// Lanes 0..29: scattering delay lines. Lanes 30..35: mic FIR rows.
// Lane 36: direct src->mic path. Lanes 37..63: idle (zero coeffs).
//
// Math per step (Householder S = 2vv^T/uu - I), perm fused into gathers:
//   p_j   = acc_prev[PERM[gb+j]] + inj
//   s     = 2 (v . p) / uu ;  pm_i = s*v_i - p_i ;  pnode = s*(v.pw) - (pw.p)
// FIR in transposed form (register z-states, 1 ring read per step).
//
// BATCHED by 8 steps: min ring delay is >= 29 samples (mic/src confined to
// the central half of the room => d_nm >= 0.625 m => D >= 29), so 8-step
// batches have no intra-batch ring hazards and next-batch reads may issue
// before this batch's writes. Ring rows carry an 8-slot mirrored extension
// so batched reads are wrap-free (merge into ds_read2_b32).

#define NN    6
#define NLn   30
#define FIRN  7
#define TCAP  4096
#define LCAP  273                // > max delay (<=261)
#define EXT   8                  // mirrored extension: slots 0..7 at 273..280
#define RSTR  (LCAP + EXT)       // 281 (odd => good bank spread)
#define PADX  264                // zero prefix: x[k-D] needs no bounds check
#define NROW  37                 // 30 lines + 6 mic + 1 dummy
#define BATCH 8

__global__ __launch_bounds__(64)
void sdn_kernel(const float* __restrict__ x, const float* __restrict__ srcp,
                const float* __restrict__ micp, const float* __restrict__ jf,
                const float* __restrict__ jv, const float* __restrict__ pw,
                float* __restrict__ out, int T)
{
    const int b = blockIdx.x;
    const int l = threadIdx.x;

    __shared__ float  rows[NROW][RSTR];
    __shared__ float  xl[PADX + TCAP + BATCH];
    __shared__ double nds[NN][3];

    for (int i = l; i < NROW * RSTR;         i += 64) (&rows[0][0])[i] = 0.f;
    for (int i = l; i < PADX + TCAP + BATCH; i += 64) xl[i] = 0.f;
    __syncthreads();
    for (int i = l; i < T; i += 64) xl[PADX + i] = x[i];

    const double room[3] = {4.0, 3.0, 2.5};
    double src[3] = {srcp[0], srcp[1], srcp[2]};
    double mic[3] = {micp[3*b+0], micp[3*b+1], micp[3*b+2]};

    if (l < NN) {
        int a = l >> 1;
        double w = (l & 1) ? room[a] : 0.0;
        double sa = (a == 0) ? src[0] : ((a == 1) ? src[1] : src[2]);
        double ma = (a == 0) ? mic[0] : ((a == 1) ? mic[1] : mic[2]);
        double ia = 2.0 * w - sa;
        double img0 = src[0], img1 = src[1], img2 = src[2];
        if (a == 0) img0 = ia; else if (a == 1) img1 = ia; else img2 = ia;
        double t = (w - ia) / (ma - ia);
        nds[l][0] = img0 + t * (mic[0] - img0);
        nds[l][1] = img1 + t * (mic[1] - img1);
        nds[l][2] = img2 + t * (mic[2] - img2);
    }
    __syncthreads();

    const double G = 343.0 / 16000.0;
    const int n = (l < NLn) ? (l / 5) : ((l < NLn + NN) ? (l - NLn) : 0);

    double dx = nds[n][0] - src[0], dy = nds[n][1] - src[1], dz = nds[n][2] - src[2];
    double dsn = sqrt(dx*dx + dy*dy + dz*dz);
    dx = nds[n][0] - mic[0]; dy = nds[n][1] - mic[1]; dz = nds[n][2] - mic[2];
    double dnm = sqrt(dx*dx + dy*dy + dz*dz);
    dx = mic[0] - src[0]; dy = mic[1] - src[1]; dz = mic[2] - src[2];
    double dsm = sqrt(dx*dx + dy*dy + dz*dz);

    const int   Dsn  = (int)rint(dsn / G);
    const int   Dsm  = (int)rint(dsm / G);
    const float srcg = (float)(0.5 * G / dsn);
    const float micg = (float)(1.0 / (1.0 + dnm / dsn));
    const float dirg = (float)(1.0 / dsm);

    int Dl;
    if (l < NLn) {
        int i5 = l / 5, mm = l % 5;
        int m = mm + (mm >= i5 ? 1 : 0);
        double ax = nds[i5][0] - nds[m][0];
        double ay = nds[i5][1] - nds[m][1];
        double az = nds[i5][2] - nds[m][2];
        Dl = (int)rint(sqrt(ax*ax + ay*ay + az*az) / G);
    } else if (l < NLn + NN) {
        Dl = (int)rint(dnm / G);
    } else {
        Dl = 64;
    }

    float srcgl; int xoff;
    if (l < NLn + NN)       { srcgl = srcg; xoff = PADX - Dsn; }
    else if (l == NLn + NN) { srcgl = dirg; xoff = PADX - Dsm; }
    else                    { srcgl = 0.f;  xoff = PADX; }

    const bool active = (l < NLn + NN);
    float v0 = active ? jv[n*5+0] : 0.f, v1 = active ? jv[n*5+1] : 0.f;
    float v2 = active ? jv[n*5+2] : 0.f, v3 = active ? jv[n*5+3] : 0.f;
    float v4 = active ? jv[n*5+4] : 0.f;
    float uu = jv[n*5+0]*jv[n*5+0] + jv[n*5+1]*jv[n*5+1] + jv[n*5+2]*jv[n*5+2]
             + jv[n*5+3]*jv[n*5+3] + jv[n*5+4]*jv[n*5+4];
    const float c2u = 2.0f / uu;
    const float SV  = v0 + v1 + v2 + v3 + v4;

    float w0, w1, w2, w3, w4, wsv, Wa;
    if (l < NLn) {
        int ir = l % 5;
        w0 = (ir==0); w1 = (ir==1); w2 = (ir==2); w3 = (ir==3); w4 = (ir==4);
        wsv = 1.f;
        Wa = (ir==0)?v0:((ir==1)?v1:((ir==2)?v2:((ir==3)?v3:v4)));
    } else if (l < NLn + NN) {
        float q0 = pw[n*5+0], q1 = pw[n*5+1], q2 = pw[n*5+2], q3 = pw[n*5+3], q4 = pw[n*5+4];
        w0 = micg*q0; w1 = micg*q1; w2 = micg*q2; w3 = micg*q3; w4 = micg*q4;
        wsv = micg * (q0+q1+q2+q3+q4);
        Wa  = micg * (v0*q0 + v1*q1 + v2*q2 + v3*q3 + v4*q4);
    } else {
        w0=w1=w2=w3=w4=0.f; wsv=0.f; Wa=0.f;
    }

    float c0,c1,c2,c3,c4,c5,c6,c7;
    {
        const float* f = jf + n*(FIRN+1);
        c0 = active ? f[7] : 0.f; c1 = active ? f[6] : 0.f;
        c2 = active ? f[5] : 0.f; c3 = active ? f[4] : 0.f;
        c4 = active ? f[3] : 0.f; c5 = active ? f[2] : 0.f;
        c6 = active ? f[1] : 0.f; c7 = active ? f[0] : 0.f;
    }

    const int gb = n * 5;
    int p0=0,p1=0,p2=0,p3=0,p4=0;
    if (active) {
        #define PERMF(i) ((6*((i)+1) - ((i)%6) - 1) % NLn)
        p0 = PERMF(gb+0); p1 = PERMF(gb+1); p2 = PERMF(gb+2);
        p3 = PERMF(gb+3); p4 = PERMF(gb+4);
        #undef PERMF
    }

    float* rowbase = rows[(l < NROW-1) ? l : NROW-1];
    const float* xpc = xl + xoff;            // points at current batch's x
    float* outp = out + b * T;

    __syncthreads();

    float z1=0.f,z2=0.f,z3=0.f,z4=0.f,z5=0.f,z6=0.f,z7=0.f;
    float accm1 = 0.f;

    int up_off = LCAP - Dl;                  // per-lane read slot (dwords)
    int wp0 = 0;                             // uniform write slot (scalar)

    const int NB = T / BATCH;

    float ub[BATCH], xb[BATCH], nu[BATCH], nx[BATCH];

    // prologue: load batch 0 inputs
    {
        const float* up = rowbase + up_off;
        #pragma unroll
        for (int i = 0; i < BATCH; ++i) ub[i] = up[i];
        up_off += BATCH; if (up_off >= LCAP) up_off -= LCAP;
        #pragma unroll
        for (int i = 0; i < BATCH; ++i) xb[i] = xpc[i];
    }

    for (int t = 0; t < NB; ++t) {
        // ---- phase A: FIR z-chains -> acc[0..7] (consumes ub/xb) ----
        float acc[BATCH], inj[BATCH];
        #pragma unroll
        for (int i = 0; i < BATCH; ++i) {
            float u  = ub[i];
            inj[i]   = srcgl * xpc[0 - 0 + 0 * i];  // placeholder avoided below
        }
        #pragma unroll
        for (int i = 0; i < BATCH; ++i) {
            float u  = ub[i];
            inj[i]   = srcgl * xb[i];
            float a  = fmaf(c0, u, z1);
            z1 = fmaf(c1, u, z2); z2 = fmaf(c2, u, z3); z3 = fmaf(c3, u, z4);
            z4 = fmaf(c4, u, z5); z5 = fmaf(c5, u, z6); z6 = fmaf(c6, u, z7);
            z7 = c7 * u;
            if (l == NLn + NN) a = inj[i];   // direct-path lane
            acc[i] = a;
        }

        // ---- phase B: prefetch next batch's u/x (latency hides under C/D) ----
        // safe: reads for steps k0+8..k0+15 need data written at <= k0-14 (Dl>=29)
        {
            const float* up = rowbase + up_off;
            #pragma unroll
            for (int i = 0; i < BATCH; ++i) nu[i] = up[i];
            up_off += BATCH; if (up_off >= LCAP) up_off -= LCAP;
            #pragma unroll
            for (int i = 0; i < BATCH; ++i) nx[i] = xpc[BATCH + i];
        }

        // ---- phase C: all 40 gathers (independent, register-sourced) ----
        float G0[BATCH], G1[BATCH], G2[BATCH], G3[BATCH], G4[BATCH];
        #pragma unroll
        for (int i = 0; i < BATCH; ++i) {
            float ap = (i == 0) ? accm1 : acc[i-1];
            G0[i] = __shfl(ap, p0);
            G1[i] = __shfl(ap, p1);
            G2[i] = __shfl(ap, p2);
            G3[i] = __shfl(ap, p3);
            G4[i] = __shfl(ap, p4);
        }

        // ---- phase D: scatter outputs, ring writes, mic sums ----
        #pragma unroll
        for (int i = 0; i < BATCH; ++i) {
            float vdot = fmaf(v0,G0[i], fmaf(v1,G1[i], fmaf(v2,G2[i],
                         fmaf(v3,G3[i], fmaf(v4,G4[i], inj[i]*SV)))));
            float s    = vdot * c2u;
            float wdot = fmaf(w0,G0[i], fmaf(w1,G1[i], fmaf(w2,G2[i],
                         fmaf(w3,G3[i], fmaf(w4,G4[i], inj[i]*wsv)))));
            float wv   = fmaf(s, Wa, -wdot);

            int sl = wp0 + i; if (sl >= LCAP) sl -= LCAP;   // scalar-uniform
            if (l < NLn + NN) {
                rowbase[sl] = wv;
                if (sl < EXT) rowbase[sl + LCAP] = wv;      // mirror (rare, uniform)
            }
        }
        #pragma unroll
        for (int i = 0; i < BATCH; ++i) {
            float ss = acc[i];
            ss += __shfl_down(ss, 1);
            ss += __shfl_down(ss, 2);
            ss += __shfl_down(ss, 4);
            if (l == NLn) outp[t * BATCH + i] = ss;
        }

        accm1 = acc[BATCH-1];
        wp0 += BATCH; if (wp0 >= LCAP) wp0 -= LCAP;
        xpc += BATCH;
        #pragma unroll
        for (int i = 0; i < BATCH; ++i) { ub[i] = nu[i]; xb[i] = nx[i]; }
    }

    // tail (T not multiple of 8) -- dead for T=4000 but kept for generality
    for (int k = NB * BATCH; k < T; ++k) {
        int ro = k - Dl; while (ro < 0) ro += LCAP; while (ro >= LCAP) ro -= LCAP;
        float u   = rowbase[ro];
        float xr  = xpc[k - NB * BATCH];
        float injv = srcgl * xr;
        float a   = fmaf(c0, u, z1);
        z1 = fmaf(c1, u, z2); z2 = fmaf(c2, u, z3); z3 = fmaf(c3, u, z4);
        z4 = fmaf(c4, u, z5); z5 = fmaf(c5, u, z6); z6 = fmaf(c6, u, z7);
        z7 = c7 * u;
        if (l == NLn + NN) a = injv;
        float g0 = __shfl(accm1, p0), g1 = __shfl(accm1, p1), g2 = __shfl(accm1, p2);
        float g3 = __shfl(accm1, p3), g4 = __shfl(accm1, p4);
        float vdot = fmaf(v0,g0, fmaf(v1,g1, fmaf(v2,g2, fmaf(v3,g3, fmaf(v4,g4, injv*SV)))));
        float s    = vdot * c2u;
        float wdot = fmaf(w0,g0, fmaf(w1,g1, fmaf(w2,g2, fmaf(w3,g3, fmaf(w4,g4, injv*wsv)))));
        float wv   = fmaf(s, Wa, -wdot);
        int sl = k % LCAP;
        if (l < NLn + NN) {
            rowbase[sl] = wv;
            if (sl < EXT) rowbase[sl + LCAP] = wv;
        }
        float ss = a;
        ss += __shfl_down(ss, 1);
        ss += __shfl_down(ss, 2);
        ss += __shfl_down(ss, 4);
        if (l == NLn) outp[k] = ss;
        accm1 = a;
    }
}

extern "C" void kernel_launch(void* const* d_in, const int* in_sizes, int n_in,
                              void* d_out, int out_size, void* d_ws, size_t ws_size,
                              hipStream_t stream)
{
    const float* x    = (const float*)d_in[0];
    const float* srcp = (const float*)d_in[1];
    const float* micp = (const float*)d_in[2];
    const float* jf   = (const float*)d_in[3];
    const float* jv   = (const float*)d_in[4];
    const float* pw   = (const float*)d_in[5];
    float* out = (float*)d_out;

    int T  = in_sizes[0];
    if (T > TCAP) T = TCAP;
    int Bc = in_sizes[2] / 3;

    sdn_kernel<<<Bc, 64, 0, stream>>>(x, srcp, micp, jf, jv, pw, out, T);
}

// Round 4
// 303.410 us; speedup vs baseline: 4.8535x; 2.6311x over previous
//
#include <hip/hip_runtime.h>
#include <math.h>

// SDN room acoustics: B=4 independent sims, one 64-lane wave each.
// Lanes 0..29: scattering delay lines. Lanes 30..35: mic FIR rows.
// Lane 36: direct src->mic path. Lanes 37..63: idle (zero coeffs).
//
// Math per step (Householder S = 2vv^T/uu - I), perm fused into gathers:
//   p_j   = acc_prev[PERM[gb+j]] + inj
//   s     = 2 (v . p) / uu ;  pm_i = s*v_i - p_i ;  pnode = s*(v.pw) - (pw.p)
// FIR in transposed form (register z-states, 1 ring read per step).
//
// Batched by S=16 steps (min ring delay >= 29 > 16 => no intra-batch hazard;
// reads-before-writes in program order returns correctly-old data).
// Ring capacity 288 (multiple of 16) => write slot wp0+i never wraps inside a
// batch; a 16-slot mirrored extension makes batched reads wrap-free, updated
// under a uniform branch only when wp0==0 (1 in 18 batches).
// Mic output via LDS staging + coalesced 16-lane store (no per-step shuffles).

#define NN    6
#define NLn   30
#define FIRN  7
#define TCAP  4000
#define LCAP  288                // ring capacity, multiple of BATCH
#define EXT   17                 // mirror extension; RSTR odd => bank spread
#define RSTR  (LCAP + EXT)       // 305
#define PADX  264                // zero prefix: x[k-D] needs no bounds check
#define NROW  37                 // 30 lines + 6 mic + 1 dummy
#define BATCH 16

__global__ __launch_bounds__(64, 1)
void sdn_kernel(const float* __restrict__ x, const float* __restrict__ srcp,
                const float* __restrict__ micp, const float* __restrict__ jf,
                const float* __restrict__ jv, const float* __restrict__ pw,
                float* __restrict__ out, int T)
{
    const int b = blockIdx.x;
    const int l = threadIdx.x;

    __shared__ float  rows[NROW][RSTR];
    __shared__ float  xl[PADX + TCAP];
    __shared__ float  st[BATCH][9];          // mic staging, stride 9 (bank-clean)
    __shared__ double nds[NN][3];

    for (int i = l; i < NROW * RSTR; i += 64) (&rows[0][0])[i] = 0.f;
    for (int i = l; i < PADX;        i += 64) xl[i] = 0.f;
    for (int i = l; i < T;           i += 64) xl[PADX + i] = x[i];

    const double room[3] = {4.0, 3.0, 2.5};
    double src[3] = {srcp[0], srcp[1], srcp[2]};
    double mic[3] = {micp[3*b+0], micp[3*b+1], micp[3*b+2]};

    if (l < NN) {
        int a = l >> 1;
        double w = (l & 1) ? room[a] : 0.0;
        double sa = (a == 0) ? src[0] : ((a == 1) ? src[1] : src[2]);
        double ma = (a == 0) ? mic[0] : ((a == 1) ? mic[1] : mic[2]);
        double ia = 2.0 * w - sa;
        double img0 = src[0], img1 = src[1], img2 = src[2];
        if (a == 0) img0 = ia; else if (a == 1) img1 = ia; else img2 = ia;
        double t = (w - ia) / (ma - ia);
        nds[l][0] = img0 + t * (mic[0] - img0);
        nds[l][1] = img1 + t * (mic[1] - img1);
        nds[l][2] = img2 + t * (mic[2] - img2);
    }
    __syncthreads();

    const double G = 343.0 / 16000.0;
    const int n = (l < NLn) ? (l / 5) : ((l < NLn + NN) ? (l - NLn) : 0);

    double dx = nds[n][0] - src[0], dy = nds[n][1] - src[1], dz = nds[n][2] - src[2];
    double dsn = sqrt(dx*dx + dy*dy + dz*dz);
    dx = nds[n][0] - mic[0]; dy = nds[n][1] - mic[1]; dz = nds[n][2] - mic[2];
    double dnm = sqrt(dx*dx + dy*dy + dz*dz);
    dx = mic[0] - src[0]; dy = mic[1] - src[1]; dz = mic[2] - src[2];
    double dsm = sqrt(dx*dx + dy*dy + dz*dz);

    const int   Dsn  = (int)rint(dsn / G);
    const int   Dsm  = (int)rint(dsm / G);
    const float srcg = (float)(0.5 * G / dsn);
    const float micg = (float)(1.0 / (1.0 + dnm / dsn));
    const float dirg = (float)(1.0 / dsm);

    int Dl;
    if (l < NLn) {
        int i5 = l / 5, mm = l % 5;
        int m = mm + (mm >= i5 ? 1 : 0);
        double ax = nds[i5][0] - nds[m][0];
        double ay = nds[i5][1] - nds[m][1];
        double az = nds[i5][2] - nds[m][2];
        Dl = (int)rint(sqrt(ax*ax + ay*ay + az*az) / G);
    } else if (l < NLn + NN) {
        Dl = (int)rint(dnm / G);
    } else {
        Dl = 64;
    }

    float srcgl; int xoff;
    if (l < NLn + NN)       { srcgl = srcg; xoff = PADX - Dsn; }
    else if (l == NLn + NN) { srcgl = dirg; xoff = PADX - Dsm; }
    else                    { srcgl = 0.f;  xoff = PADX; }

    const bool active = (l < NLn + NN);
    float v0 = active ? jv[n*5+0] : 0.f, v1 = active ? jv[n*5+1] : 0.f;
    float v2 = active ? jv[n*5+2] : 0.f, v3 = active ? jv[n*5+3] : 0.f;
    float v4 = active ? jv[n*5+4] : 0.f;
    float uu = jv[n*5+0]*jv[n*5+0] + jv[n*5+1]*jv[n*5+1] + jv[n*5+2]*jv[n*5+2]
             + jv[n*5+3]*jv[n*5+3] + jv[n*5+4]*jv[n*5+4];
    const float c2u = 2.0f / uu;
    const float SV  = v0 + v1 + v2 + v3 + v4;

    float w0, w1, w2, w3, w4, wsv, Wa;
    if (l < NLn) {
        int ir = l % 5;
        w0 = (ir==0); w1 = (ir==1); w2 = (ir==2); w3 = (ir==3); w4 = (ir==4);
        wsv = 1.f;
        Wa = (ir==0)?v0:((ir==1)?v1:((ir==2)?v2:((ir==3)?v3:v4)));
    } else if (l < NLn + NN) {
        float q0 = pw[n*5+0], q1 = pw[n*5+1], q2 = pw[n*5+2], q3 = pw[n*5+3], q4 = pw[n*5+4];
        w0 = micg*q0; w1 = micg*q1; w2 = micg*q2; w3 = micg*q3; w4 = micg*q4;
        wsv = micg * (q0+q1+q2+q3+q4);
        Wa  = micg * (v0*q0 + v1*q1 + v2*q2 + v3*q3 + v4*q4);
    } else {
        w0=w1=w2=w3=w4=0.f; wsv=0.f; Wa=0.f;
    }

    float c0,c1,c2,c3,c4,c5,c6,c7;
    {
        const float* f = jf + n*(FIRN+1);
        c0 = active ? f[7] : 0.f; c1 = active ? f[6] : 0.f;
        c2 = active ? f[5] : 0.f; c3 = active ? f[4] : 0.f;
        c4 = active ? f[3] : 0.f; c5 = active ? f[2] : 0.f;
        c6 = active ? f[1] : 0.f; c7 = active ? f[0] : 0.f;
    }

    const int gb = n * 5;
    int p0=0,p1=0,p2=0,p3=0,p4=0;
    if (active) {
        #define PERMF(i) ((6*((i)+1) - ((i)%6) - 1) % NLn)
        p0 = PERMF(gb+0); p1 = PERMF(gb+1); p2 = PERMF(gb+2);
        p3 = PERMF(gb+3); p4 = PERMF(gb+4);
        #undef PERMF
    }

    float* rowbase = rows[(l < NROW-1) ? l : NROW-1];
    const float* xpc = xl + xoff;
    float* outp = out + b * T;

    __syncthreads();

    float z1=0.f,z2=0.f,z3=0.f,z4=0.f,z5=0.f,z6=0.f,z7=0.f;
    float accm1 = 0.f;

    int up_off = LCAP - Dl;                  // in [27, 259]
    int wp0 = 0;                             // multiple of 16, cycles mod 288

    const int NB = T / BATCH;

    for (int t = 0; t < NB; ++t) {
        // ---- A: issue all ring/x reads for this batch (one wait) ----
        float ub[BATCH], xb[BATCH];
        {
            const float* up = rowbase + up_off;   // reads up to up_off+15 <= 302 < RSTR
            #pragma unroll
            for (int i = 0; i < BATCH; ++i) ub[i] = up[i];
            #pragma unroll
            for (int i = 0; i < BATCH; ++i) xb[i] = xpc[i];
            up_off += BATCH; if (up_off >= LCAP) up_off -= LCAP;
        }

        // ---- B: FIR z-chains -> acc[0..15] ----
        float acc[BATCH], inj[BATCH];
        #pragma unroll
        for (int i = 0; i < BATCH; ++i) {
            float u  = ub[i];
            inj[i]   = srcgl * xb[i];
            float a  = fmaf(c0, u, z1);
            z1 = fmaf(c1, u, z2); z2 = fmaf(c2, u, z3); z3 = fmaf(c3, u, z4);
            z4 = fmaf(c4, u, z5); z5 = fmaf(c5, u, z6); z6 = fmaf(c6, u, z7);
            z7 = c7 * u;
            if (l == NLn + NN) a = inj[i];   // direct-path lane
            acc[i] = a;
        }

        // ---- C: all 80 gathers (independent; sources are registers) ----
        float G0[BATCH], G1[BATCH], G2[BATCH], G3[BATCH], G4[BATCH];
        #pragma unroll
        for (int i = 0; i < BATCH; ++i) {
            float ap = (i == 0) ? accm1 : acc[i-1];
            G0[i] = __shfl(ap, p0);
            G1[i] = __shfl(ap, p1);
            G2[i] = __shfl(ap, p2);
            G3[i] = __shfl(ap, p3);
            G4[i] = __shfl(ap, p4);
        }

        // ---- D: scatter values ----
        float wv[BATCH];
        #pragma unroll
        for (int i = 0; i < BATCH; ++i) {
            float vdot = fmaf(v0,G0[i], fmaf(v1,G1[i], fmaf(v2,G2[i],
                         fmaf(v3,G3[i], fmaf(v4,G4[i], inj[i]*SV)))));
            float s    = vdot * c2u;
            float wdot = fmaf(w0,G0[i], fmaf(w1,G1[i], fmaf(w2,G2[i],
                         fmaf(w3,G3[i], fmaf(w4,G4[i], inj[i]*wsv)))));
            wv[i]      = fmaf(s, Wa, -wdot);
        }

        // ring writes: one exec-mask region, no per-step wrap (wp0+15 <= 287)
        if (l < NLn + NN) {
            #pragma unroll
            for (int i = 0; i < BATCH; ++i) rowbase[wp0 + i] = wv[i];
        }
        // mirror region update (uniform branch, 1 in 18 batches)
        if (wp0 == 0) {
            if (l < NLn + NN) {
                #pragma unroll
                for (int i = 0; i < BATCH; ++i) rowbase[LCAP + i] = wv[i];
            }
        }

        // ---- E: mic staging ----
        if (l >= NLn && l < NLn + NN + 1) {
            #pragma unroll
            for (int i = 0; i < BATCH; ++i) st[i][l - NLn] = acc[i];
        }

        // ---- F: coalesced output (lanes 0..15) ----
        if (l < BATCH) {
            float ssum = st[l][0] + st[l][1] + st[l][2] + st[l][3]
                       + st[l][4] + st[l][5] + st[l][6];
            outp[t * BATCH + l] = ssum;
        }

        accm1 = acc[BATCH-1];
        wp0 += BATCH; if (wp0 >= LCAP) wp0 -= LCAP;
        xpc += BATCH;
    }

    // tail (T not multiple of 16) -- dead for T=4000, kept for generality
    for (int k = NB * BATCH; k < T; ++k) {
        float u   = rowbase[up_off];
        up_off++; if (up_off >= LCAP) up_off -= LCAP;
        float xr  = xpc[k - NB * BATCH];
        float injv = srcgl * xr;
        float a   = fmaf(c0, u, z1);
        z1 = fmaf(c1, u, z2); z2 = fmaf(c2, u, z3); z3 = fmaf(c3, u, z4);
        z4 = fmaf(c4, u, z5); z5 = fmaf(c5, u, z6); z6 = fmaf(c6, u, z7);
        z7 = c7 * u;
        if (l == NLn + NN) a = injv;
        float g0 = __shfl(accm1, p0), g1 = __shfl(accm1, p1), g2 = __shfl(accm1, p2);
        float g3 = __shfl(accm1, p3), g4 = __shfl(accm1, p4);
        float vdot = fmaf(v0,g0, fmaf(v1,g1, fmaf(v2,g2, fmaf(v3,g3, fmaf(v4,g4, injv*SV)))));
        float s    = vdot * c2u;
        float wdot = fmaf(w0,g0, fmaf(w1,g1, fmaf(w2,g2, fmaf(w3,g3, fmaf(w4,g4, injv*wsv)))));
        float wvv  = fmaf(s, Wa, -wdot);
        int sl = wp0; wp0++; if (wp0 >= LCAP) wp0 -= LCAP;
        if (l < NLn + NN) {
            rowbase[sl] = wvv;
            if (sl < EXT - 1) rowbase[sl + LCAP] = wvv;
        }
        if (l >= NLn && l < NLn + NN + 1) st[0][l - NLn] = a;
        __builtin_amdgcn_s_waitcnt(0);       // lgkm drain before cross-lane read
        if (l == 0) {
            float ssum = st[0][0] + st[0][1] + st[0][2] + st[0][3]
                       + st[0][4] + st[0][5] + st[0][6];
            outp[k] = ssum;
        }
        accm1 = a;
    }
}

extern "C" void kernel_launch(void* const* d_in, const int* in_sizes, int n_in,
                              void* d_out, int out_size, void* d_ws, size_t ws_size,
                              hipStream_t stream)
{
    const float* x    = (const float*)d_in[0];
    const float* srcp = (const float*)d_in[1];
    const float* micp = (const float*)d_in[2];
    const float* jf   = (const float*)d_in[3];
    const float* jv   = (const float*)d_in[4];
    const float* pw   = (const float*)d_in[5];
    float* out = (float*)d_out;

    int T  = in_sizes[0];
    if (T > TCAP) T = TCAP;
    int Bc = in_sizes[2] / 3;

    sdn_kernel<<<Bc, 64, 0, stream>>>(x, srcp, micp, jf, jv, pw, out, T);
}

// Round 6
// 274.250 us; speedup vs baseline: 5.3695x; 1.1063x over previous
//
#include <hip/hip_runtime.h>
#include <math.h>

// SDN room acoustics: B=4 independent sims, one 64-lane wave each.
// Lanes 0..29: scattering delay lines. Lanes 30..35: mic FIR rows.
// Lane 36: direct src->mic path. Lanes 37..63: idle (zero coeffs).
//
// Math per step (Householder S = 2vv^T/uu - I), perm fused into gathers:
//   p_j   = acc_prev[PERM[gb+j]] + inj
//   s     = 2 (v . p) / uu ;  pm_i = s*v_i - p_i ;  pnode = s*(v.pw) - (pw.p)
// FIR in transposed form (register z-states, 1 ring read per step).
//
// Batched by 16 steps (min ring delay >= 29 samples: mic/src are confined to
// the central half of the room => d_nm >= 0.625 m => D >= 29; node-node
// >= 1.25 m => D >= 58). Phases pinned with sched_barrier(0): all DS ops of
// a phase issue back-to-back; in-order DS completion => one rolling lgkmcnt
// wait per phase instead of one ~120-cycle round-trip per step.

#define NN    6
#define NLn   30
#define FIRN  7
#define TCAP  4000
#define LCAP  288                // ring capacity, multiple of BATCH
#define EXT   18                 // mirror extension; RSTR even => f2-aligned
#define RSTR  (LCAP + EXT)       // 306
#define PADX  264                // zero prefix: x[k-D] needs no bounds check
#define NROW  37                 // 30 lines + 6 mic + 1 dummy
#define BATCH 16

typedef float f2 __attribute__((ext_vector_type(2)));

__global__ __launch_bounds__(64, 1)
void sdn_kernel(const float* __restrict__ x, const float* __restrict__ srcp,
                const float* __restrict__ micp, const float* __restrict__ jf,
                const float* __restrict__ jv, const float* __restrict__ pw,
                float* __restrict__ out, int T)
{
    const int b = blockIdx.x;
    const int l = threadIdx.x;

    __shared__ __align__(16) float rows[NROW][RSTR];
    __shared__ float  xl[PADX + TCAP];
    __shared__ __align__(16) float st[NN + 1][20];   // mic staging [row][step]
    __shared__ double nds[NN][3];

    for (int i = l; i < NROW * RSTR; i += 64) (&rows[0][0])[i] = 0.f;
    for (int i = l; i < PADX;        i += 64) xl[i] = 0.f;
    for (int i = l; i < T;           i += 64) xl[PADX + i] = x[i];

    const double room[3] = {4.0, 3.0, 2.5};
    double src[3] = {srcp[0], srcp[1], srcp[2]};
    double mic[3] = {micp[3*b+0], micp[3*b+1], micp[3*b+2]};

    if (l < NN) {
        int a = l >> 1;
        double w = (l & 1) ? room[a] : 0.0;
        double sa = (a == 0) ? src[0] : ((a == 1) ? src[1] : src[2]);
        double ma = (a == 0) ? mic[0] : ((a == 1) ? mic[1] : mic[2]);
        double ia = 2.0 * w - sa;
        double img0 = src[0], img1 = src[1], img2 = src[2];
        if (a == 0) img0 = ia; else if (a == 1) img1 = ia; else img2 = ia;
        double t = (w - ia) / (ma - ia);
        nds[l][0] = img0 + t * (mic[0] - img0);
        nds[l][1] = img1 + t * (mic[1] - img1);
        nds[l][2] = img2 + t * (mic[2] - img2);
    }
    __syncthreads();

    const double G = 343.0 / 16000.0;
    const int n = (l < NLn) ? (l / 5) : ((l < NLn + NN) ? (l - NLn) : 0);

    double dx = nds[n][0] - src[0], dy = nds[n][1] - src[1], dz = nds[n][2] - src[2];
    double dsn = sqrt(dx*dx + dy*dy + dz*dz);
    dx = nds[n][0] - mic[0]; dy = nds[n][1] - mic[1]; dz = nds[n][2] - mic[2];
    double dnm = sqrt(dx*dx + dy*dy + dz*dz);
    dx = mic[0] - src[0]; dy = mic[1] - src[1]; dz = mic[2] - src[2];
    double dsm = sqrt(dx*dx + dy*dy + dz*dz);

    const int   Dsn  = (int)rint(dsn / G);
    const int   Dsm  = (int)rint(dsm / G);
    const float srcg = (float)(0.5 * G / dsn);
    const float micg = (float)(1.0 / (1.0 + dnm / dsn));
    const float dirg = (float)(1.0 / dsm);

    int Dl;
    if (l < NLn) {
        int i5 = l / 5, mm = l % 5;
        int m = mm + (mm >= i5 ? 1 : 0);
        double ax = nds[i5][0] - nds[m][0];
        double ay = nds[i5][1] - nds[m][1];
        double az = nds[i5][2] - nds[m][2];
        Dl = (int)rint(sqrt(ax*ax + ay*ay + az*az) / G);
    } else if (l < NLn + NN) {
        Dl = (int)rint(dnm / G);
    } else {
        Dl = 64;
    }

    float srcgl; int xoff;
    if (l < NLn + NN)       { srcgl = srcg; xoff = PADX - Dsn; }
    else if (l == NLn + NN) { srcgl = dirg; xoff = PADX - Dsm; }
    else                    { srcgl = 0.f;  xoff = PADX; }

    const bool active = (l < NLn + NN);
    float v0 = active ? jv[n*5+0] : 0.f, v1 = active ? jv[n*5+1] : 0.f;
    float v2 = active ? jv[n*5+2] : 0.f, v3 = active ? jv[n*5+3] : 0.f;
    float v4 = active ? jv[n*5+4] : 0.f;
    float uu = jv[n*5+0]*jv[n*5+0] + jv[n*5+1]*jv[n*5+1] + jv[n*5+2]*jv[n*5+2]
             + jv[n*5+3]*jv[n*5+3] + jv[n*5+4]*jv[n*5+4];
    const float c2u = 2.0f / uu;
    const float SV  = v0 + v1 + v2 + v3 + v4;

    float w0, w1, w2, w3, w4, wsv, Wa;
    if (l < NLn) {
        int ir = l % 5;
        w0 = (ir==0); w1 = (ir==1); w2 = (ir==2); w3 = (ir==3); w4 = (ir==4);
        wsv = 1.f;
        Wa = (ir==0)?v0:((ir==1)?v1:((ir==2)?v2:((ir==3)?v3:v4)));
    } else if (l < NLn + NN) {
        float q0 = pw[n*5+0], q1 = pw[n*5+1], q2 = pw[n*5+2], q3 = pw[n*5+3], q4 = pw[n*5+4];
        w0 = micg*q0; w1 = micg*q1; w2 = micg*q2; w3 = micg*q3; w4 = micg*q4;
        wsv = micg * (q0+q1+q2+q3+q4);
        Wa  = micg * (v0*q0 + v1*q1 + v2*q2 + v3*q3 + v4*q4);
    } else {
        w0=w1=w2=w3=w4=0.f; wsv=0.f; Wa=0.f;
    }

    float c0,c1,c2,c3,c4,c5,c6,c7;
    {
        const float* f = jf + n*(FIRN+1);
        c0 = active ? f[7] : 0.f; c1 = active ? f[6] : 0.f;
        c2 = active ? f[5] : 0.f; c3 = active ? f[4] : 0.f;
        c4 = active ? f[3] : 0.f; c5 = active ? f[2] : 0.f;
        c6 = active ? f[1] : 0.f; c7 = active ? f[0] : 0.f;
    }

    const int gb = n * 5;
    int p0=0,p1=0,p2=0,p3=0,p4=0;
    if (active) {
        #define PERMF(i) ((6*((i)+1) - ((i)%6) - 1) % NLn)
        p0 = PERMF(gb+0); p1 = PERMF(gb+1); p2 = PERMF(gb+2);
        p3 = PERMF(gb+3); p4 = PERMF(gb+4);
        #undef PERMF
    }

    float* rowbase = rows[(l < NROW-1) ? l : NROW-1];
    const float* xpc = xl + xoff;
    float* outp = out + b * T;

    __syncthreads();

    float z1=0.f,z2=0.f,z3=0.f,z4=0.f,z5=0.f,z6=0.f,z7=0.f;
    float accm1 = 0.f;

    int up_off = LCAP - Dl;                  // in [29, 259]
    int wp0 = 0;                             // multiple of 16, cycles mod 288

    const int NB = T / BATCH;

    for (int t = 0; t < NB; ++t) {
        // ---- A: issue all ring/x reads for this batch ----
        float ub[BATCH], xb[BATCH];
        {
            const float* up = rowbase + up_off;   // up to up_off+15 <= 302 < RSTR
            #pragma unroll
            for (int i = 0; i < BATCH; ++i) ub[i] = up[i];
            #pragma unroll
            for (int i = 0; i < BATCH; ++i) xb[i] = xpc[i];
            up_off += BATCH; if (up_off >= LCAP) up_off -= LCAP;
        }
        __builtin_amdgcn_sched_barrier(0);

        // ---- B: FIR z-chains -> acc[0..15] ----
        float acc[BATCH], inj[BATCH];
        #pragma unroll
        for (int i = 0; i < BATCH; ++i) {
            float u  = ub[i];
            inj[i]   = srcgl * xb[i];
            float a  = fmaf(c0, u, z1);
            z1 = fmaf(c1, u, z2); z2 = fmaf(c2, u, z3); z3 = fmaf(c3, u, z4);
            z4 = fmaf(c4, u, z5); z5 = fmaf(c5, u, z6); z6 = fmaf(c6, u, z7);
            z7 = c7 * u;
            if (l == NLn + NN) a = inj[i];   // direct-path lane
            acc[i] = a;
        }
        __builtin_amdgcn_sched_barrier(0);

        // ---- C: all 80 gathers issued back-to-back ----
        float G0[BATCH], G1[BATCH], G2[BATCH], G3[BATCH], G4[BATCH];
        #pragma unroll
        for (int i = 0; i < BATCH; ++i) {
            float ap = (i == 0) ? accm1 : acc[i-1];
            G0[i] = __shfl(ap, p0);
            G1[i] = __shfl(ap, p1);
            G2[i] = __shfl(ap, p2);
            G3[i] = __shfl(ap, p3);
            G4[i] = __shfl(ap, p4);
        }
        __builtin_amdgcn_sched_barrier(0);

        // ---- D: vdot/wdot chains, then scatter value ----
        float wv[BATCH];
        #pragma unroll
        for (int i = 0; i < BATCH; ++i) {
            float vdot = fmaf(v0,G0[i], fmaf(v1,G1[i], fmaf(v2,G2[i],
                         fmaf(v3,G3[i], fmaf(v4,G4[i], inj[i]*SV)))));
            float s    = vdot * c2u;
            float wdot = fmaf(w0,G0[i], fmaf(w1,G1[i], fmaf(w2,G2[i],
                         fmaf(w3,G3[i], fmaf(w4,G4[i], inj[i]*wsv)))));
            wv[i]      = fmaf(s, Wa, -wdot);
        }

        // ring writes: paired f2 stores, no wrap inside batch (wp0+15 <= 287)
        if (l < NLn + NN) {
            #pragma unroll
            for (int j = 0; j < BATCH/2; ++j)
                *(f2*)(rowbase + wp0 + 2*j) = (f2){wv[2*j], wv[2*j+1]};
        }
        // mirror region update (uniform branch, 1 in 18 batches)
        if (wp0 == 0) {
            if (l < NLn + NN) {
                #pragma unroll
                for (int j = 0; j < BATCH/2; ++j)
                    *(f2*)(rowbase + LCAP + 2*j) = (f2){wv[2*j], wv[2*j+1]};
            }
        }

        // ---- E: mic staging, transposed [row][step], float4 writes ----
        if (l >= NLn && l <= NLn + NN) {
            float* srow = st[l - NLn];
            #pragma unroll
            for (int j = 0; j < BATCH/4; ++j)
                *(float4*)(srow + 4*j) =
                    make_float4(acc[4*j], acc[4*j+1], acc[4*j+2], acc[4*j+3]);
        }

        // ---- F: coalesced output (lanes 0..15 sum 7 rows) ----
        if (l < BATCH) {
            float ssum = ((st[0][l] + st[1][l]) + (st[2][l] + st[3][l]))
                       + ((st[4][l] + st[5][l]) + st[6][l]);
            outp[t * BATCH + l] = ssum;
        }

        accm1 = acc[BATCH-1];
        wp0 += BATCH; if (wp0 >= LCAP) wp0 -= LCAP;
        xpc += BATCH;
    }

    // tail (T not multiple of 16) -- dead for T=4000, kept for generality
    for (int k = NB * BATCH; k < T; ++k) {
        float u   = rowbase[up_off];
        up_off++; if (up_off >= LCAP) up_off -= LCAP;
        float xr  = xpc[k - NB * BATCH];
        float injv = srcgl * xr;
        float a   = fmaf(c0, u, z1);
        z1 = fmaf(c1, u, z2); z2 = fmaf(c2, u, z3); z3 = fmaf(c3, u, z4);
        z4 = fmaf(c4, u, z5); z5 = fmaf(c5, u, z6); z6 = fmaf(c6, u, z7);
        z7 = c7 * u;
        if (l == NLn + NN) a = injv;
        float g0 = __shfl(accm1, p0), g1 = __shfl(accm1, p1), g2 = __shfl(accm1, p2);
        float g3 = __shfl(accm1, p3), g4 = __shfl(accm1, p4);
        float vdot = fmaf(v0,g0, fmaf(v1,g1, fmaf(v2,g2, fmaf(v3,g3, fmaf(v4,g4, injv*SV)))));
        float s    = vdot * c2u;
        float wdot = fmaf(w0,g0, fmaf(w1,g1, fmaf(w2,g2, fmaf(w3,g3, fmaf(w4,g4, injv*wsv)))));
        float wvv  = fmaf(s, Wa, -wdot);
        int sl = wp0; wp0++; if (wp0 >= LCAP) wp0 -= LCAP;
        if (l < NLn + NN) {
            rowbase[sl] = wvv;
            if (sl < BATCH) rowbase[sl + LCAP] = wvv;
        }
        if (l >= NLn && l <= NLn + NN) st[l - NLn][0] = a;
        __builtin_amdgcn_s_waitcnt(0);
        if (l == 0) {
            float ssum = st[0][0] + st[1][0] + st[2][0] + st[3][0]
                       + st[4][0] + st[5][0] + st[6][0];
            outp[k] = ssum;
        }
        accm1 = a;
    }
}

extern "C" void kernel_launch(void* const* d_in, const int* in_sizes, int n_in,
                              void* d_out, int out_size, void* d_ws, size_t ws_size,
                              hipStream_t stream)
{
    const float* x    = (const float*)d_in[0];
    const float* srcp = (const float*)d_in[1];
    const float* micp = (const float*)d_in[2];
    const float* jf   = (const float*)d_in[3];
    const float* jv   = (const float*)d_in[4];
    const float* pw   = (const float*)d_in[5];
    float* out = (float*)d_out;

    int T  = in_sizes[0];
    if (T > TCAP) T = TCAP;
    int Bc = in_sizes[2] / 3;

    sdn_kernel<<<Bc, 64, 0, stream>>>(x, srcp, micp, jf, jv, pw, out, T);
}

// Round 7
// 189.308 us; speedup vs baseline: 7.7788x; 1.4487x over previous
//
#include <hip/hip_runtime.h>
#include <math.h>

// SDN room acoustics: B=4 independent sims, one 256-thread block (4 waves) each.
// Within a wave: lanes 0..29 = scattering delay lines, 30..35 = mic FIR rows,
// 36 = direct src->mic path, 37..63 idle. All 4 waves carry the full 37-row
// lane layout; wave w owns steps {4w..4w+3} of each 16-step batch.
//
// Per step (Householder S = 2vv^T/uu - I), perm fused into gathers:
//   p_j = acc(k-1)[PERM[gb+j]] + inj ; s = 2(v.p)/uu
//   line: wv = s*v_ir - p_ir ; mic: wv = micg*(s*(v.q) - q.p)
// FIR in DIRECT form (no state): acc(k) = c7*u(k-7) +..+ c0*u(k) — same
// association as the transposed z-chain => bit-identical. Each wave computes
// acc for steps 4w-1..4w+3 locally (5 FIRs from 12 ring reads), so gathers
// (intra-wave bpermute) need no cross-wave traffic. Cross-wave ordering only
// via one __syncthreads per batch: writes(t) before reads(t+1). Safe because
// all delays >= 29 samples (d_nn >= 1.25 m => D >= 58; d_nm >= 0.625 m =>
// D >= 29; mic/src confined to central half of room).

#define NN    6
#define NLn   30
#define NACT  36                 // 30 lines + 6 mic
#define FIRN  7
#define TCAP  4096
#define LCAP  288                // ring capacity, multiple of BATCH
#define EXT   20                 // mirror extension; RSTR multiple of 4
#define RSTR  (LCAP + EXT)       // 308
#define PADX  264                // zero prefix: x[k-D] needs no bounds check
#define NROW  37                 // 36 active + 1 dummy
#define BATCH 16
#define SPW   4                  // steps per wave

__global__ __launch_bounds__(256, 1)
void sdn_kernel(const float* __restrict__ x, const float* __restrict__ srcp,
                const float* __restrict__ micp, const float* __restrict__ jf,
                const float* __restrict__ jv, const float* __restrict__ pw,
                float* __restrict__ out, int T)
{
    const int b   = blockIdx.x;
    const int l   = threadIdx.x;
    const int wl  = l & 63;
    const int wid = l >> 6;

    __shared__ __align__(16) float rows[NROW][RSTR];
    __shared__ float  xl[PADX + TCAP];
    __shared__ __align__(16) float st[NN + 1][20];   // mic staging [row][step]
    __shared__ double nds[NN][3];

    for (int i = l; i < NROW * RSTR; i += 256) (&rows[0][0])[i] = 0.f;
    for (int i = l; i < PADX;        i += 256) xl[i] = 0.f;
    for (int i = l; i < T;           i += 256) xl[PADX + i] = x[i];

    const double room[3] = {4.0, 3.0, 2.5};
    double src[3] = {srcp[0], srcp[1], srcp[2]};
    double mic[3] = {micp[3*b+0], micp[3*b+1], micp[3*b+2]};

    if (l < NN) {
        int a = l >> 1;
        double w = (l & 1) ? room[a] : 0.0;
        double sa = (a == 0) ? src[0] : ((a == 1) ? src[1] : src[2]);
        double ma = (a == 0) ? mic[0] : ((a == 1) ? mic[1] : mic[2]);
        double ia = 2.0 * w - sa;
        double img0 = src[0], img1 = src[1], img2 = src[2];
        if (a == 0) img0 = ia; else if (a == 1) img1 = ia; else img2 = ia;
        double t = (w - ia) / (ma - ia);
        nds[l][0] = img0 + t * (mic[0] - img0);
        nds[l][1] = img1 + t * (mic[1] - img1);
        nds[l][2] = img2 + t * (mic[2] - img2);
    }
    __syncthreads();

    const double G = 343.0 / 16000.0;
    const int n = (wl < NLn) ? (wl / 5) : ((wl < NACT) ? (wl - NLn) : 0);

    double dx = nds[n][0] - src[0], dy = nds[n][1] - src[1], dz = nds[n][2] - src[2];
    double dsn = sqrt(dx*dx + dy*dy + dz*dz);
    dx = nds[n][0] - mic[0]; dy = nds[n][1] - mic[1]; dz = nds[n][2] - mic[2];
    double dnm = sqrt(dx*dx + dy*dy + dz*dz);
    dx = mic[0] - src[0]; dy = mic[1] - src[1]; dz = mic[2] - src[2];
    double dsm = sqrt(dx*dx + dy*dy + dz*dz);

    const int   Dsn  = (int)rint(dsn / G);
    const int   Dsm  = (int)rint(dsm / G);
    const float srcg = (float)(0.5 * G / dsn);
    const float micg = (float)(1.0 / (1.0 + dnm / dsn));
    const float dirg = (float)(1.0 / dsm);

    int Dl;
    if (wl < NLn) {
        int i5 = wl / 5, mm = wl % 5;
        int m = mm + (mm >= i5 ? 1 : 0);            // PAIRS[(i,m)], m != i
        double ax = nds[i5][0] - nds[m][0];
        double ay = nds[i5][1] - nds[m][1];
        double az = nds[i5][2] - nds[m][2];
        Dl = (int)rint(sqrt(ax*ax + ay*ay + az*az) / G);
    } else if (wl < NACT) {
        Dl = (int)rint(dnm / G);
    } else {
        Dl = 64;                                    // dummy row
    }

    float srcgl; int xoff;
    if (wl < NACT)       { srcgl = srcg; xoff = PADX - Dsn; }
    else if (wl == NACT) { srcgl = dirg; xoff = PADX - Dsm; }
    else                 { srcgl = 0.f;  xoff = PADX; }

    const bool active = (wl < NACT);
    float v0 = active ? jv[n*5+0] : 0.f, v1 = active ? jv[n*5+1] : 0.f;
    float v2 = active ? jv[n*5+2] : 0.f, v3 = active ? jv[n*5+3] : 0.f;
    float v4 = active ? jv[n*5+4] : 0.f;
    float uu = jv[n*5+0]*jv[n*5+0] + jv[n*5+1]*jv[n*5+1] + jv[n*5+2]*jv[n*5+2]
             + jv[n*5+3]*jv[n*5+3] + jv[n*5+4]*jv[n*5+4];
    const float c2u = 2.0f / uu;
    const float SV  = v0 + v1 + v2 + v3 + v4;

    float w0, w1, w2, w3, w4, wsv, Wa;
    if (wl < NLn) {
        int ir = wl % 5;
        w0 = (ir==0); w1 = (ir==1); w2 = (ir==2); w3 = (ir==3); w4 = (ir==4);
        wsv = 1.f;
        Wa = (ir==0)?v0:((ir==1)?v1:((ir==2)?v2:((ir==3)?v3:v4)));
    } else if (wl < NACT) {
        float q0 = pw[n*5+0], q1 = pw[n*5+1], q2 = pw[n*5+2], q3 = pw[n*5+3], q4 = pw[n*5+4];
        w0 = micg*q0; w1 = micg*q1; w2 = micg*q2; w3 = micg*q3; w4 = micg*q4;
        wsv = micg * (q0+q1+q2+q3+q4);
        Wa  = micg * (v0*q0 + v1*q1 + v2*q2 + v3*q3 + v4*q4);
    } else {
        w0=w1=w2=w3=w4=0.f; wsv=0.f; Wa=0.f;
    }

    float c0,c1,c2,c3,c4,c5,c6,c7;
    {
        const float* f = jf + n*(FIRN+1);
        c0 = active ? f[7] : 0.f; c1 = active ? f[6] : 0.f;
        c2 = active ? f[5] : 0.f; c3 = active ? f[4] : 0.f;
        c4 = active ? f[3] : 0.f; c5 = active ? f[2] : 0.f;
        c6 = active ? f[1] : 0.f; c7 = active ? f[0] : 0.f;
    }

    const int gb = n * 5;
    int p0=0,p1=0,p2=0,p3=0,p4=0;
    if (active) {
        #define PERMF(i) ((6*((i)+1) - ((i)%6) - 1) % NLn)
        p0 = PERMF(gb+0); p1 = PERMF(gb+1); p2 = PERMF(gb+2);
        p3 = PERMF(gb+3); p4 = PERMF(gb+4);
        #undef PERMF
    }

    float* rowbase = rows[(wl < NROW-1) ? wl : NROW-1];
    const float* xpc = xl + xoff;
    float* outp = out + b * T;

    __syncthreads();

    const int k0off = SPW * wid;             // 0,4,8,12: this wave's step offset
    // read base: slot of u(k0-8) = (t*16 + k0off - 8 - Dl) mod 288
    int up_off = ((k0off - 8 - Dl) % LCAP + LCAP) % LCAP;
    int wp0 = 0;                             // uniform, multiple of 16

    const int NB = T / BATCH;

    for (int t = 0; t < NB; ++t) {
        // ---- A: 12 ring reads (u(k0-8..k0+3)) + 4 x reads ----
        float u[12], xq[SPW];
        #pragma unroll
        for (int j = 0; j < 12; ++j) u[j] = rowbase[up_off + j];   // <= 298 < RSTR
        #pragma unroll
        for (int i = 0; i < SPW; ++i) xq[i] = xpc[t*BATCH + k0off + i];
        up_off += BATCH; if (up_off >= LCAP) up_off -= LCAP;
        __builtin_amdgcn_sched_barrier(0);

        // ---- B: 5 direct-form FIRs (steps k0-1 .. k0+3), bit-identical assoc ----
        float accs[SPW+1];
        #pragma unroll
        for (int s = 0; s <= SPW; ++s) {
            float a = c7 * u[s];
            a = fmaf(c6, u[s+1], a); a = fmaf(c5, u[s+2], a);
            a = fmaf(c4, u[s+3], a); a = fmaf(c3, u[s+4], a);
            a = fmaf(c2, u[s+5], a); a = fmaf(c1, u[s+6], a);
            a = fmaf(c0, u[s+7], a);
            accs[s] = a;
        }
        float inj[SPW];
        #pragma unroll
        for (int i = 0; i < SPW; ++i) inj[i] = srcgl * xq[i];
        if (wl == NACT) {                    // direct-path lane
            accs[1] = inj[0]; accs[2] = inj[1]; accs[3] = inj[2]; accs[4] = inj[3];
        }
        __builtin_amdgcn_sched_barrier(0);

        // ---- C: 20 gathers, all independent ----
        float G0[SPW], G1[SPW], G2[SPW], G3[SPW], G4[SPW];
        #pragma unroll
        for (int i = 0; i < SPW; ++i) {
            float ap = accs[i];              // acc(k0+i-1)
            G0[i] = __shfl(ap, p0);
            G1[i] = __shfl(ap, p1);
            G2[i] = __shfl(ap, p2);
            G3[i] = __shfl(ap, p3);
            G4[i] = __shfl(ap, p4);
        }
        __builtin_amdgcn_sched_barrier(0);

        // ---- D: scatter values, ring write, mic staging, output ----
        float wv[SPW];
        #pragma unroll
        for (int i = 0; i < SPW; ++i) {
            float vdot = fmaf(v0,G0[i], fmaf(v1,G1[i], fmaf(v2,G2[i],
                         fmaf(v3,G3[i], fmaf(v4,G4[i], inj[i]*SV)))));
            float s    = vdot * c2u;
            float wdot = fmaf(w0,G0[i], fmaf(w1,G1[i], fmaf(w2,G2[i],
                         fmaf(w3,G3[i], fmaf(w4,G4[i], inj[i]*wsv)))));
            wv[i]      = fmaf(s, Wa, -wdot);
        }

        if (wl < NACT)
            *(float4*)(rowbase + wp0 + k0off) =
                make_float4(wv[0], wv[1], wv[2], wv[3]);
        if (wp0 == 0) {                      // mirror (uniform, 1 in 18 batches)
            if (wl < NACT)
                *(float4*)(rowbase + LCAP + k0off) =
                    make_float4(wv[0], wv[1], wv[2], wv[3]);
        }

        if (wl >= NLn && wl <= NACT)
            *(float4*)(st[wl - NLn] + k0off) =
                make_float4(accs[1], accs[2], accs[3], accs[4]);

        if (wl < SPW) {
            int col = k0off + wl;
            float ssum = ((st[0][col] + st[1][col]) + (st[2][col] + st[3][col]))
                       + ((st[4][col] + st[5][col]) + st[6][col]);
            outp[t * BATCH + col] = ssum;
        }

        wp0 += BATCH; if (wp0 >= LCAP) wp0 -= LCAP;
        __syncthreads();                     // writes(t) before reads(t+1)
    }

    // tail (T not multiple of 16) -- dead for T=4000, wave 0 only, no barriers
    if ((T & (BATCH - 1)) && wid == 0) {
        int kstart = NB * BATCH;
        // acc(kstart-1)
        float accPrev;
        {
            int base = kstart - 1 - Dl;
            int i0 = base - 7; i0 %= LCAP; if (i0 < 0) i0 += LCAP;
            float a = c7 * rowbase[i0];
            #define TAP(cc, off) { int ii = base - (off); ii %= LCAP; if (ii < 0) ii += LCAP; a = fmaf(cc, rowbase[ii], a); }
            TAP(c6,6) TAP(c5,5) TAP(c4,4) TAP(c3,3) TAP(c2,2) TAP(c1,1) TAP(c0,0)
            accPrev = a;
        }
        for (int k = kstart; k < T; ++k) {
            float injv = srcgl * xpc[k];
            if (wl == NACT) accPrev = (k == kstart) ? (srcgl * xpc[k-1]) : accPrev;
            float g0 = __shfl(accPrev, p0), g1 = __shfl(accPrev, p1);
            float g2 = __shfl(accPrev, p2), g3 = __shfl(accPrev, p3);
            float g4 = __shfl(accPrev, p4);
            float vdot = fmaf(v0,g0, fmaf(v1,g1, fmaf(v2,g2, fmaf(v3,g3, fmaf(v4,g4, injv*SV)))));
            float s    = vdot * c2u;
            float wdot = fmaf(w0,g0, fmaf(w1,g1, fmaf(w2,g2, fmaf(w3,g3, fmaf(w4,g4, injv*wsv)))));
            float wvv  = fmaf(s, Wa, -wdot);
            int sl = k % LCAP;
            if (wl < NACT) {
                rowbase[sl] = wvv;
                if (sl < BATCH) rowbase[sl + LCAP] = wvv;
            }
            // acc(k) for next iter + mic output
            int base = k - Dl;
            int i0 = base - 7; i0 %= LCAP; if (i0 < 0) i0 += LCAP;
            float a = c7 * rowbase[i0];
            TAP(c6,6) TAP(c5,5) TAP(c4,4) TAP(c3,3) TAP(c2,2) TAP(c1,1) TAP(c0,0)
            #undef TAP
            if (wl == NACT) a = injv;
            if (wl >= NLn && wl <= NACT) st[wl - NLn][0] = a;
            __builtin_amdgcn_s_waitcnt(0);
            if (wl == 0) {
                float ssum = ((st[0][0] + st[1][0]) + (st[2][0] + st[3][0]))
                           + ((st[4][0] + st[5][0]) + st[6][0]);
                outp[k] = ssum;
            }
            accPrev = a;
        }
    }
}

extern "C" void kernel_launch(void* const* d_in, const int* in_sizes, int n_in,
                              void* d_out, int out_size, void* d_ws, size_t ws_size,
                              hipStream_t stream)
{
    const float* x    = (const float*)d_in[0];
    const float* srcp = (const float*)d_in[1];
    const float* micp = (const float*)d_in[2];
    const float* jf   = (const float*)d_in[3];
    const float* jv   = (const float*)d_in[4];
    const float* pw   = (const float*)d_in[5];
    float* out = (float*)d_out;

    int T  = in_sizes[0];
    if (T > TCAP) T = TCAP;
    int Bc = in_sizes[2] / 3;

    sdn_kernel<<<Bc, 256, 0, stream>>>(x, srcp, micp, jf, jv, pw, out, T);
}

// Round 10
// 148.161 us; speedup vs baseline: 9.9392x; 1.2777x over previous
//
#include <hip/hip_runtime.h>
#include <math.h>

// SDN room acoustics: B=4 independent sims, one 256-thread block (4 waves) each.
// Lane layout (8-aligned node groups, bpermute-free):
//   lane 8n+j, j<5 : line PERM-source reader for line i=n*5+j (node n)
//   lane 8n+5     : mic FIR row of node n
//   lane 6        : direct src->mic path (group-0 pad; butterfly weight 0)
//   other pads    : idle (weights 0, dummy row)
// Key idea: the line permutation is folded into the ring READ — lane for line i
// reads row PERM[i] with PERM[i]'s delay & node coeffs, so p_i = FIR + inj is
// lane-local. The two per-node dots A=sum(v_j p_j), B=sum(micg q_j p_j) are
// computed with DPP butterflies (quad_perm xor1/xor2 + masked row_shr/shl:4
// cross-quad exchange) — pure VALU, no DS ops. The mic lane sits inside the
// group and receives A,B for free.  wv_line = s*v - p, wv_mic = s*Wa - B,
// s = 2A/uu.  FIR in direct form (8 taps from 12 batched ring reads).
//
// Batched by 20 steps (min delay >= 29: mic/src confined to central half of
// room => d_nm >= 0.625 m => D >= 29; d_nn >= 1.25 m => D >= 58). One
// __syncthreads per batch orders writes(t) before reads(t+1). LCAP=300 makes
// the in-batch overwrite window older than the oldest read, so no wrap race
// even for D=261. Ring stride 313 = 25 mod 32 (coprime) => full bank spread.

#define NN    6
#define NLn   30
#define FIRN  7
#define TLEN  4000
#define LCAP  300                // ring capacity, multiple of BATCH
#define EXT   13                 // mirror extension (reads reach LCAP+10)
#define RSTR  (LCAP + EXT)       // 313, odd, 25 mod 32
#define PADX  264                // zero prefix: x[k-D] needs no bounds check
#define NROW  37                 // 30 line rows + 6 mic rows + 1 dummy
#define BATCH 20
#define SPW   5                  // steps per wave
#define NU    (SPW + FIRN)       // 12 ring reads per batch per lane

template<int CTRL>
__device__ __forceinline__ float dpp_xor_add(float x) {
    int m = __builtin_amdgcn_update_dpp(0, __float_as_int(x), CTRL, 0xF, 0xF, false);
    return x + __int_as_float(m);
}
// value from lane i^4 within each 8-lane group:
//   row_shr:4 writes dest banks 1,3 (lanes 4-7,12-15 <- 0-3,8-11)
//   row_shl:4 writes dest banks 0,2 (lanes 0-3,8-11 <- 4-7,12-15)
__device__ __forceinline__ float dpp_xquad(float x) {
    int xi = __float_as_int(x);
    int m = __builtin_amdgcn_update_dpp(0, xi, 0x114, 0xF, 0xA, false); // row_shr:4
    m     = __builtin_amdgcn_update_dpp(m, xi, 0x104, 0xF, 0x5, false); // row_shl:4
    return __int_as_float(m);
}

__global__ __launch_bounds__(256, 1)
void sdn_kernel(const float* __restrict__ x, const float* __restrict__ srcp,
                const float* __restrict__ micp, const float* __restrict__ jf,
                const float* __restrict__ jv, const float* __restrict__ pw,
                float* __restrict__ out, int T)
{
    const int b   = blockIdx.x;
    const int l   = threadIdx.x;
    const int wl  = l & 63;
    const int wid = l >> 6;

    __shared__ float  rows[NROW][RSTR];
    __shared__ float  xl[PADX + TLEN];
    __shared__ float  st[NN + 1][25];        // mic staging [row][step], stride 25
    __shared__ double nds[NN][3];

    for (int i = l; i < NROW * RSTR; i += 256) (&rows[0][0])[i] = 0.f;
    for (int i = l; i < PADX;        i += 256) xl[i] = 0.f;
    for (int i = l; i < T;           i += 256) xl[PADX + i] = x[i];

    const double room[3] = {4.0, 3.0, 2.5};
    double src[3] = {srcp[0], srcp[1], srcp[2]};
    double mic[3] = {micp[3*b+0], micp[3*b+1], micp[3*b+2]};

    if (l < NN) {
        int a = l >> 1;
        double w = (l & 1) ? room[a] : 0.0;
        double sa = (a == 0) ? src[0] : ((a == 1) ? src[1] : src[2]);
        double ma = (a == 0) ? mic[0] : ((a == 1) ? mic[1] : mic[2]);
        double ia = 2.0 * w - sa;
        double img0 = src[0], img1 = src[1], img2 = src[2];
        if (a == 0) img0 = ia; else if (a == 1) img1 = ia; else img2 = ia;
        double t = (w - ia) / (ma - ia);
        nds[l][0] = img0 + t * (mic[0] - img0);
        nds[l][1] = img1 + t * (mic[1] - img1);
        nds[l][2] = img2 + t * (mic[2] - img2);
    }
    __syncthreads();

    const double G = 343.0 / 16000.0;
    const int n  = (wl < 48) ? (wl >> 3) : 0;
    const int ir = wl & 7;
    const bool isline = (wl < 48) && (ir < 5);
    const bool ismic  = (wl < 48) && (ir == 5);
    const bool isdir  = (wl == 6);

    const int lineid = n * 5 + ir;                       // valid when isline
    #define PERMF(i) ((6*((i)+1) - ((i)%6) - 1) % NLn)
    const int srcl = PERMF(lineid % NLn);                // source line we read
    #undef PERMF
    const int ns = srcl / 5;                             // source line's node

    // own-node geometry (inj, micg, uu)
    double dx = nds[n][0] - src[0], dy = nds[n][1] - src[1], dz = nds[n][2] - src[2];
    double dsn = sqrt(dx*dx + dy*dy + dz*dz);
    dx = nds[n][0] - mic[0]; dy = nds[n][1] - mic[1]; dz = nds[n][2] - mic[2];
    double dnm = sqrt(dx*dx + dy*dy + dz*dz);
    dx = mic[0] - src[0]; dy = mic[1] - src[1]; dz = mic[2] - src[2];
    double dsm = sqrt(dx*dx + dy*dy + dz*dz);

    const int   Dsn  = (int)rint(dsn / G);
    const int   Dsm  = (int)rint(dsm / G);
    const float srcg = (float)(0.5 * G / dsn);
    const float micg = (float)(1.0 / (1.0 + dnm / dsn));
    const float dirg = (float)(1.0 / dsm);

    // delay of the row this lane READS
    int Dline;
    {
        int mm = srcl % 5;
        int m2 = mm + (mm >= ns ? 1 : 0);                // PAIRS of source line
        double ax = nds[ns][0] - nds[m2][0];
        double ay = nds[ns][1] - nds[m2][1];
        double az = nds[ns][2] - nds[m2][2];
        Dline = (int)rint(sqrt(ax*ax + ay*ay + az*az) / G);
    }
    const int Dmic = (int)rint(dnm / G);
    const int D = isline ? Dline : (ismic ? Dmic : 64);

    // injection (own node for lines; direct lane uses dsm path)
    float srcgl; int xoff;
    if (isline)      { srcgl = srcg; xoff = PADX - Dsn; }
    else if (isdir)  { srcgl = dirg; xoff = PADX - Dsm; }
    else             { srcgl = 0.f;  xoff = PADX; }

    // FIR coefficients: node of the row we read (source line's node / own node)
    const int nc = isline ? ns : n;
    const bool hasfir = isline || ismic;
    float c0,c1,c2,c3,c4,c5,c6,c7;
    {
        const float* f = jf + nc*(FIRN+1);
        c0 = hasfir ? f[7] : 0.f; c1 = hasfir ? f[6] : 0.f;
        c2 = hasfir ? f[5] : 0.f; c3 = hasfir ? f[4] : 0.f;
        c4 = hasfir ? f[3] : 0.f; c5 = hasfir ? f[2] : 0.f;
        c6 = hasfir ? f[1] : 0.f; c7 = hasfir ? f[0] : 0.f;
    }

    // butterfly weights and write-value constants
    const float uu = jv[n*5+0]*jv[n*5+0] + jv[n*5+1]*jv[n*5+1] + jv[n*5+2]*jv[n*5+2]
                   + jv[n*5+3]*jv[n*5+3] + jv[n*5+4]*jv[n*5+4];
    const float c2u = 2.0f / uu;
    const float vw = isline ? jv[n*5+ir] : 0.f;                  // v_j weight
    const float qw = isline ? micg * pw[n*5+ir] : 0.f;           // micg*q_j weight
    float Wa;
    if (isline) Wa = vw;
    else if (ismic) {
        Wa = micg * (jv[n*5+0]*pw[n*5+0] + jv[n*5+1]*pw[n*5+1] + jv[n*5+2]*pw[n*5+2]
                   + jv[n*5+3]*pw[n*5+3] + jv[n*5+4]*pw[n*5+4]);
    } else Wa = 0.f;

    // row pointers
    const int rdrow = isline ? srcl : (ismic ? NLn + n : NROW - 1);
    const int wrrow = isline ? lineid : (ismic ? NLn + n : NROW - 1);
    const bool haswrite = isline || ismic;
    const bool hasstage = ismic || isdir;
    float* rdbase = rows[rdrow];
    float* wrbase = rows[wrrow];
    float* strow  = st[ismic ? n : 6];
    const float* xpc = xl + xoff;
    float* outp = out + b * T;

    __syncthreads();

    const int k0off = SPW * wid;                 // 0,5,10,15
    const int shift = isline ? 8 : 7;            // u window start: k0-shift-D
    int up_off = ((k0off - shift - D) % LCAP + LCAP) % LCAP;
    int wp0 = 0;

    const int NB = T / BATCH;

    for (int t = 0; t < NB; ++t) {
        // ---- A: 12 ring reads + 5 x reads ----
        float u[NU], xq[SPW];
        #pragma unroll
        for (int j = 0; j < NU; ++j) u[j] = rdbase[up_off + j];  // <= 299+11 < 313
        #pragma unroll
        for (int i = 0; i < SPW; ++i) xq[i] = xpc[t*BATCH + k0off + i];
        up_off += BATCH; if (up_off >= LCAP) up_off -= LCAP;
        __builtin_amdgcn_sched_barrier(0);

        // ---- B: 5 direct-form FIRs + injection -> p ----
        float fir[SPW], inj[SPW], p[SPW];
        #pragma unroll
        for (int i = 0; i < SPW; ++i) {
            float a = c7 * u[i];
            a = fmaf(c6, u[i+1], a); a = fmaf(c5, u[i+2], a);
            a = fmaf(c4, u[i+3], a); a = fmaf(c3, u[i+4], a);
            a = fmaf(c2, u[i+5], a); a = fmaf(c1, u[i+6], a);
            a = fmaf(c0, u[i+7], a);
            inj[i] = srcgl * xq[i];
            if (isdir) a = inj[i];               // direct path output
            fir[i] = a;
            p[i] = a + inj[i];
        }

        // ---- C: DPP butterflies -> A,B per group; write values ----
        float wv[SPW];
        #pragma unroll
        for (int i = 0; i < SPW; ++i) {
            float tv = vw * p[i];
            float tq = qw * p[i];
            tv = dpp_xor_add<0xB1>(tv); tq = dpp_xor_add<0xB1>(tq);  // xor1
            tv = dpp_xor_add<0x4E>(tv); tq = dpp_xor_add<0x4E>(tq);  // xor2
            float Av = tv + dpp_xquad(tv);                            // + other quad
            float Bv = tq + dpp_xquad(tq);
            float s  = Av * c2u;
            wv[i] = fmaf(s, Wa, -(ismic ? Bv : p[i]));
        }

        // ---- D: ring writes (+ mirror), mic staging, output ----
        if (haswrite) {
            #pragma unroll
            for (int i = 0; i < SPW; ++i) wrbase[wp0 + k0off + i] = wv[i];
        }
        if (wp0 == 0) {                          // uniform, 1 in 15 batches
            if (haswrite) {
                #pragma unroll
                for (int i = 0; i < SPW; ++i)
                    if (k0off + i < EXT) wrbase[LCAP + k0off + i] = wv[i];
            }
        }
        if (hasstage) {
            #pragma unroll
            for (int i = 0; i < SPW; ++i) strow[k0off + i] = fir[i];
        }
        if (wl < SPW) {
            int col = k0off + wl;
            float ssum = ((st[0][col] + st[1][col]) + (st[2][col] + st[3][col]))
                       + ((st[4][col] + st[5][col]) + st[6][col]);
            outp[t * BATCH + col] = ssum;
        }

        wp0 += BATCH; if (wp0 >= LCAP) wp0 -= LCAP;
        __syncthreads();                         // writes(t) before reads(t+1)
    }

    // tail (T not multiple of 20) -- dead for T=4000; wave 0, per-step
    if ((T % BATCH) && wid == 0) {
        for (int k = NB * BATCH; k < T; ++k) {
            float injv = srcgl * xpc[k];
            int m = k - (isline ? 1 : 0);        // FIR step
            int base = m - D;
            #define RIDX(o) (((base - (o)) % LCAP + LCAP) % LCAP)
            float a = c7 * rdbase[RIDX(7)];
            a = fmaf(c6, rdbase[RIDX(6)], a);
            a = fmaf(c5, rdbase[RIDX(5)], a);
            a = fmaf(c4, rdbase[RIDX(4)], a);
            a = fmaf(c3, rdbase[RIDX(3)], a);
            a = fmaf(c2, rdbase[RIDX(2)], a);
            a = fmaf(c1, rdbase[RIDX(1)], a);
            a = fmaf(c0, rdbase[RIDX(0)], a);
            #undef RIDX
            if (isdir) a = injv;
            float pv = a + injv;
            float tv = vw * pv, tq = qw * pv;
            tv = dpp_xor_add<0xB1>(tv); tq = dpp_xor_add<0xB1>(tq);
            tv = dpp_xor_add<0x4E>(tv); tq = dpp_xor_add<0x4E>(tq);
            float Av = tv + dpp_xquad(tv);
            float Bv = tq + dpp_xquad(tq);
            float s  = Av * c2u;
            float wvv = fmaf(s, Wa, -(ismic ? Bv : pv));
            int sl = k % LCAP;
            if (haswrite) {
                wrbase[sl] = wvv;
                if (sl < EXT) wrbase[sl + LCAP] = wvv;
            }
            if (hasstage) strow[0] = a;
            __builtin_amdgcn_s_waitcnt(0);
            if (wl == 0) {
                float ssum = ((st[0][0] + st[1][0]) + (st[2][0] + st[3][0]))
                           + ((st[4][0] + st[5][0]) + st[6][0]);
                outp[k] = ssum;
            }
        }
    }
}

extern "C" void kernel_launch(void* const* d_in, const int* in_sizes, int n_in,
                              void* d_out, int out_size, void* d_ws, size_t ws_size,
                              hipStream_t stream)
{
    const float* x    = (const float*)d_in[0];
    const float* srcp = (const float*)d_in[1];
    const float* micp = (const float*)d_in[2];
    const float* jf   = (const float*)d_in[3];
    const float* jv   = (const float*)d_in[4];
    const float* pw   = (const float*)d_in[5];
    float* out = (float*)d_out;

    int T  = in_sizes[0];
    if (T > TLEN) T = TLEN;
    int Bc = in_sizes[2] / 3;

    sdn_kernel<<<Bc, 256, 0, stream>>>(x, srcp, micp, jf, jv, pw, out, T);
}

// Round 11
// 129.983 us; speedup vs baseline: 11.3291x; 1.1398x over previous
//
#include <hip/hip_runtime.h>
#include <math.h>

// SDN room acoustics: B=4 independent sims, one 256-thread block (4 waves) each.
// Lane layout (8-aligned node groups, bpermute-free):
//   lane 8n+j, j<5 : line PERM-source reader for line i=n*5+j (node n)
//   lane 8n+5     : mic FIR row of node n
//   lane 6        : direct src->mic path (group-0 pad; butterfly weight 0)
//   other pads    : idle (weights 0, dummy row)
// The line permutation is folded into the ring READ (lane for line i reads row
// PERM[i] with PERM[i]'s delay & node coeffs) so p_i = FIR + inj is lane-local.
// Per-node dots A=sum(v_j p_j), B=sum(micg q_j p_j) via DPP butterflies (pure
// VALU). wv_line = s*v - p, wv_mic = s*Wa - B, s = 2A/uu. FIR in direct form.
//
// Batched by 28 steps (D >= 29 for all rows: mic/src confined to central half
// of room => d_nm >= 0.625 m => D >= 29; lines: nodes on different walls =>
// d_nn >= ~0.98 m => D >= 46). One __syncthreads per batch orders writes(t)
// before reads(t+1). LCAP=308: in-batch overwrite window older than oldest
// read (269 < 281) => no wrap race. RSTR=321 == 1 mod 32 => full bank spread.
//
// PREFETCH: batch t+1's u/x reads issue at the END of batch t (after this
// wave's ring writes; LDS aliasing orders them). The barrier's lgkmcnt(0)
// drains them => FIR starts with zero wait. Lanes whose newest prefetched
// step could be written by OTHER lanes during batch t (D < 42-shift+k0off)
// re-read after the barrier under an exec-masked branch (skipped when empty).

#define NN    6
#define NLn   30
#define FIRN  7
#define TLEN  4000
#define LCAP  308                // ring capacity, 11*BATCH
#define EXT   13                 // mirror extension (reads reach LCAP+12)
#define RSTR  (LCAP + EXT)       // 321 == 1 mod 32
#define PADX  264                // zero prefix: x[k-D] needs no bounds check
#define XPAD  64                 // zero tail: last partial batch reads x=0
#define NROW  37                 // 30 line rows + 6 mic rows + 1 dummy
#define BATCH 28
#define SPW   7                  // steps per wave
#define NU    (SPW + FIRN)       // 14 ring reads per batch per lane

template<int CTRL>
__device__ __forceinline__ float dpp_xor_add(float x) {
    int m = __builtin_amdgcn_update_dpp(0, __float_as_int(x), CTRL, 0xF, 0xF, false);
    return x + __int_as_float(m);
}
// value from lane i^4 within each 8-lane group:
//   row_shr:4 writes dest banks 1,3 (lanes 4-7,12-15 <- 0-3,8-11)
//   row_shl:4 writes dest banks 0,2 (lanes 0-3,8-11 <- 4-7,12-15)
__device__ __forceinline__ float dpp_xquad(float x) {
    int xi = __float_as_int(x);
    int m = __builtin_amdgcn_update_dpp(0, xi, 0x114, 0xF, 0xA, false); // row_shr:4
    m     = __builtin_amdgcn_update_dpp(m, xi, 0x104, 0xF, 0x5, false); // row_shl:4
    return __int_as_float(m);
}

__global__ __launch_bounds__(256, 1)
void sdn_kernel(const float* __restrict__ x, const float* __restrict__ srcp,
                const float* __restrict__ micp, const float* __restrict__ jf,
                const float* __restrict__ jv, const float* __restrict__ pw,
                float* __restrict__ out, int T)
{
    const int b   = blockIdx.x;
    const int l   = threadIdx.x;
    const int wl  = l & 63;
    const int wid = l >> 6;

    __shared__ float  rows[NROW][RSTR];
    __shared__ float  xl[PADX + TLEN + XPAD];
    __shared__ float  st[NN + 1][29];        // mic staging [row][step]
    __shared__ double nds[NN][3];

    for (int i = l; i < NROW * RSTR;        i += 256) (&rows[0][0])[i] = 0.f;
    for (int i = l; i < PADX + TLEN + XPAD; i += 256) xl[i] = 0.f;
    __syncthreads();
    for (int i = l; i < T; i += 256) xl[PADX + i] = x[i];

    const double room[3] = {4.0, 3.0, 2.5};
    double src[3] = {srcp[0], srcp[1], srcp[2]};
    double mic[3] = {micp[3*b+0], micp[3*b+1], micp[3*b+2]};

    if (l < NN) {
        int a = l >> 1;
        double w = (l & 1) ? room[a] : 0.0;
        double sa = (a == 0) ? src[0] : ((a == 1) ? src[1] : src[2]);
        double ma = (a == 0) ? mic[0] : ((a == 1) ? mic[1] : mic[2]);
        double ia = 2.0 * w - sa;
        double img0 = src[0], img1 = src[1], img2 = src[2];
        if (a == 0) img0 = ia; else if (a == 1) img1 = ia; else img2 = ia;
        double t = (w - ia) / (ma - ia);
        nds[l][0] = img0 + t * (mic[0] - img0);
        nds[l][1] = img1 + t * (mic[1] - img1);
        nds[l][2] = img2 + t * (mic[2] - img2);
    }
    __syncthreads();

    const double G = 343.0 / 16000.0;
    const int n  = (wl < 48) ? (wl >> 3) : 0;
    const int ir = wl & 7;
    const bool isline = (wl < 48) && (ir < 5);
    const bool ismic  = (wl < 48) && (ir == 5);
    const bool isdir  = (wl == 6);

    const int lineid = n * 5 + ir;                       // valid when isline
    #define PERMF(i) ((6*((i)+1) - ((i)%6) - 1) % NLn)
    const int srcl = PERMF(lineid % NLn);                // source line we read
    #undef PERMF
    const int ns = srcl / 5;                             // source line's node

    // own-node geometry (inj, micg, uu)
    double dx = nds[n][0] - src[0], dy = nds[n][1] - src[1], dz = nds[n][2] - src[2];
    double dsn = sqrt(dx*dx + dy*dy + dz*dz);
    dx = nds[n][0] - mic[0]; dy = nds[n][1] - mic[1]; dz = nds[n][2] - mic[2];
    double dnm = sqrt(dx*dx + dy*dy + dz*dz);
    dx = mic[0] - src[0]; dy = mic[1] - src[1]; dz = mic[2] - src[2];
    double dsm = sqrt(dx*dx + dy*dy + dz*dz);

    const int   Dsn  = (int)rint(dsn / G);
    const int   Dsm  = (int)rint(dsm / G);
    const float srcg = (float)(0.5 * G / dsn);
    const float micg = (float)(1.0 / (1.0 + dnm / dsn));
    const float dirg = (float)(1.0 / dsm);

    // delay of the row this lane READS
    int Dline;
    {
        int mm = srcl % 5;
        int m2 = mm + (mm >= ns ? 1 : 0);                // PAIRS of source line
        double ax = nds[ns][0] - nds[m2][0];
        double ay = nds[ns][1] - nds[m2][1];
        double az = nds[ns][2] - nds[m2][2];
        Dline = (int)rint(sqrt(ax*ax + ay*ay + az*az) / G);
    }
    const int Dmic = (int)rint(dnm / G);
    const int D = isline ? Dline : (ismic ? Dmic : 64);

    // injection (own node for lines; direct lane uses dsm path)
    float srcgl; int xoff;
    if (isline || ismic) { srcgl = srcg; xoff = PADX - Dsn; }
    else if (isdir)      { srcgl = dirg; xoff = PADX - Dsm; }
    else                 { srcgl = 0.f;  xoff = PADX; }

    // FIR coefficients: node of the row we read (source line's node / own node)
    const int nc = isline ? ns : n;
    const bool hasfir = isline || ismic;
    float c0,c1,c2,c3,c4,c5,c6,c7;
    {
        const float* f = jf + nc*(FIRN+1);
        c0 = hasfir ? f[7] : 0.f; c1 = hasfir ? f[6] : 0.f;
        c2 = hasfir ? f[5] : 0.f; c3 = hasfir ? f[4] : 0.f;
        c4 = hasfir ? f[3] : 0.f; c5 = hasfir ? f[2] : 0.f;
        c6 = hasfir ? f[1] : 0.f; c7 = hasfir ? f[0] : 0.f;
    }

    // butterfly weights and write-value constants
    const float uu = jv[n*5+0]*jv[n*5+0] + jv[n*5+1]*jv[n*5+1] + jv[n*5+2]*jv[n*5+2]
                   + jv[n*5+3]*jv[n*5+3] + jv[n*5+4]*jv[n*5+4];
    const float c2u = 2.0f / uu;
    const float vw = isline ? jv[n*5+ir] : 0.f;                  // v_j weight
    const float qw = isline ? micg * pw[n*5+ir] : 0.f;           // micg*q_j weight
    float Wa;
    if (isline) Wa = vw;
    else if (ismic) {
        Wa = micg * (jv[n*5+0]*pw[n*5+0] + jv[n*5+1]*pw[n*5+1] + jv[n*5+2]*pw[n*5+2]
                   + jv[n*5+3]*pw[n*5+3] + jv[n*5+4]*pw[n*5+4]);
    } else Wa = 0.f;

    // row pointers
    const int rdrow = isline ? srcl : (ismic ? NLn + n : NROW - 1);
    const int wrrow = isline ? lineid : (ismic ? NLn + n : NROW - 1);
    const bool haswrite = isline || ismic;
    const bool hasstage = ismic || isdir;
    float* rdbase = rows[rdrow];
    float* wrbase = rows[wrrow];
    float* strow  = st[ismic ? n : 6];
    const float* xpc = xl + xoff;
    float* outp = out + b * T;

    const int k0off = SPW * wid;                 // 0,7,14,21
    const int shift = isline ? 8 : 7;            // u window: k0-shift-D+j
    // prefetch-unsafe: newest prefetched step may be written by OTHER lanes
    // during the overlapped batch. newest = tB + k0off + 14 - shift + B - D.
    const bool needrr = (D < (42 - shift + k0off));

    __syncthreads();

    int cur_off = ((k0off - shift - D) % LCAP + LCAP) % LCAP;
    int wp0 = 0;
    const int NB = (T + BATCH - 1) / BATCH;      // 143 for T=4000

    float u[NU], xq[SPW];
    // prologue: prefetch batch 0 (ring is zero-initialized)
    #pragma unroll
    for (int j = 0; j < NU; ++j) u[j] = rdbase[cur_off + j];
    #pragma unroll
    for (int i = 0; i < SPW; ++i) xq[i] = xpc[k0off + i];
    int nxt_off = cur_off + BATCH; if (nxt_off >= LCAP) nxt_off -= LCAP;

    for (int t = 0; t < NB; ++t) {
        // ---- re-read for prefetch-unsafe lanes (execz-skipped when none) ----
        if (needrr) {
            #pragma unroll
            for (int j = 0; j < NU; ++j) u[j] = rdbase[cur_off + j];
        }

        // ---- B: direct-form FIRs + injection -> p ----
        float fir[SPW], inj[SPW], p[SPW];
        #pragma unroll
        for (int i = 0; i < SPW; ++i) {
            float a = c7 * u[i];
            a = fmaf(c6, u[i+1], a); a = fmaf(c5, u[i+2], a);
            a = fmaf(c4, u[i+3], a); a = fmaf(c3, u[i+4], a);
            a = fmaf(c2, u[i+5], a); a = fmaf(c1, u[i+6], a);
            a = fmaf(c0, u[i+7], a);
            inj[i] = srcgl * xq[i];
            if (isdir) a = inj[i];               // direct path output
            fir[i] = a;
            p[i] = a + inj[i];
        }

        // ---- C: DPP butterflies -> A,B per group; write values ----
        float wv[SPW];
        #pragma unroll
        for (int i = 0; i < SPW; ++i) {
            float tv = vw * p[i];
            float tq = qw * p[i];
            tv = dpp_xor_add<0xB1>(tv); tq = dpp_xor_add<0xB1>(tq);  // xor1
            tv = dpp_xor_add<0x4E>(tv); tq = dpp_xor_add<0x4E>(tq);  // xor2
            float Av = tv + dpp_xquad(tv);                            // + other quad
            float Bv = tq + dpp_xquad(tq);
            float s  = Av * c2u;
            wv[i] = fmaf(s, Wa, -(ismic ? Bv : p[i]));
        }

        // ---- D: ring writes (+ mirror), mic staging ----
        if (haswrite) {
            #pragma unroll
            for (int i = 0; i < SPW; ++i) wrbase[wp0 + k0off + i] = wv[i];
        }
        if (wp0 == 0) {                          // uniform, 1 in 11 batches
            if (haswrite) {
                #pragma unroll
                for (int i = 0; i < SPW; ++i)
                    if (k0off + i < EXT) wrbase[LCAP + k0off + i] = wv[i];
            }
        }
        if (hasstage) {
            #pragma unroll
            for (int i = 0; i < SPW; ++i) strow[k0off + i] = fir[i];
        }

        // ---- prefetch batch t+1 (after ring writes: LDS aliasing orders; ----
        // ---- same-lane in-order covers mic; cross-lane handled by needrr) ----
        cur_off = nxt_off;
        #pragma unroll
        for (int j = 0; j < NU; ++j) u[j] = rdbase[cur_off + j];
        #pragma unroll
        for (int i = 0; i < SPW; ++i) xq[i] = xpc[(t+1)*BATCH + k0off + i];
        nxt_off += BATCH; if (nxt_off >= LCAP) nxt_off -= LCAP;

        // ---- F: coalesced output (lanes 0..6 sum 7 staged rows) ----
        if (wl < SPW) {
            int col  = k0off + wl;
            int gidx = t * BATCH + col;
            if (gidx < T) {
                float ssum = ((st[0][col] + st[1][col]) + (st[2][col] + st[3][col]))
                           + ((st[4][col] + st[5][col]) + st[6][col]);
                outp[gidx] = ssum;
            }
        }

        wp0 += BATCH; if (wp0 >= LCAP) wp0 -= LCAP;
        __syncthreads();                         // writes(t) before reads(t+1)
    }
}

extern "C" void kernel_launch(void* const* d_in, const int* in_sizes, int n_in,
                              void* d_out, int out_size, void* d_ws, size_t ws_size,
                              hipStream_t stream)
{
    const float* x    = (const float*)d_in[0];
    const float* srcp = (const float*)d_in[1];
    const float* micp = (const float*)d_in[2];
    const float* jf   = (const float*)d_in[3];
    const float* jv   = (const float*)d_in[4];
    const float* pw   = (const float*)d_in[5];
    float* out = (float*)d_out;

    int T  = in_sizes[0];
    if (T > TLEN) T = TLEN;
    int Bc = in_sizes[2] / 3;

    sdn_kernel<<<Bc, 256, 0, stream>>>(x, srcp, micp, jf, jv, pw, out, T);
}

// Round 12
// 122.813 us; speedup vs baseline: 11.9905x; 1.0584x over previous
//
#include <hip/hip_runtime.h>
#include <math.h>

// SDN room acoustics: B=4 independent sims, one 256-thread block (4 waves) each.
// Lane layout (8-aligned node groups, bpermute-free):
//   lane 8n+j, j<5 : line PERM-source reader for line i=n*5+j (node n)
//   lane 8n+5     : mic FIR row of node n
//   lane 6        : direct src->mic path (group-0 pad; butterfly weight 0)
//   other pads    : idle (weights 0, dummy row)
// The line permutation is folded into the ring READ (lane for line i reads row
// PERM[i] with PERM[i]'s delay & node coeffs) so p_i = FIR + inj is lane-local.
// Per-node dots A=sum(v_j p_j), B=sum(micg q_j p_j) via DPP butterflies (pure
// VALU). wv_line = s*v - p, wv_mic = s*Wa - B, s = 2A/uu. FIR in direct form.
//
// BANK EQUALIZATION: each ring row has exactly ONE reader lane, so each row
// gets a private rotation s[row] in [0,32) making its reader's LDS bank ==
// (reader_lane & 31): lanes 0..31 distinct banks, 32..47 2-way (free), pads
// broadcast. Static because (1) batch advance rotates banks uniformly
// (+28 mod 32), (2) LCAP = 448 == 0 mod 32 so ring wrap preserves phase.
//
// Batched by 28 steps (all D >= 29: mic/src confined to central half of room
// => d_nm >= 0.625 m => D >= 29). One __syncthreads per batch orders
// writes(t) before reads(t+1). LCAP=448 >> 269+28 => no wrap race ever.
// PREFETCH: batch t+1's u/x reads issue at the END of batch t; the barrier's
// lgkmcnt(0) drains them => FIR starts with zero wait. Lanes whose prefetch
// could race other waves' batch-t writes (D < 42-shift+k0off) re-read after
// the barrier under an exec-masked branch.

#define NN    6
#define NLn   30
#define FIRN  7
#define TLEN  4000
#define LCAP  448                // ring capacity: 16*BATCH, == 0 mod 32
#define EXT   13                 // mirror extension (reads reach LCAP+12)
#define HEAD  32                 // per-row rotation headroom
#define RSTRA (LCAP + EXT + HEAD) // 493
#define PADX  264                // zero prefix: x[k-D] needs no bounds check
#define XPAD  64                 // zero tail: last partial batch reads x=0
#define NROW  37                 // 30 line rows + 6 mic rows + 1 dummy
#define BATCH 28
#define SPW   7                  // steps per wave
#define NU    (SPW + FIRN)       // 14 ring reads per batch per lane

template<int CTRL>
__device__ __forceinline__ float dpp_xor_add(float x) {
    int m = __builtin_amdgcn_update_dpp(0, __float_as_int(x), CTRL, 0xF, 0xF, false);
    return x + __int_as_float(m);
}
// value from lane i^4 within each 8-lane group:
//   row_shr:4 writes dest banks 1,3 (lanes 4-7,12-15 <- 0-3,8-11)
//   row_shl:4 writes dest banks 0,2 (lanes 0-3,8-11 <- 4-7,12-15)
__device__ __forceinline__ float dpp_xquad(float x) {
    int xi = __float_as_int(x);
    int m = __builtin_amdgcn_update_dpp(0, xi, 0x114, 0xF, 0xA, false); // row_shr:4
    m     = __builtin_amdgcn_update_dpp(m, xi, 0x104, 0xF, 0x5, false); // row_shl:4
    return __int_as_float(m);
}

__global__ __launch_bounds__(256, 1)
void sdn_kernel(const float* __restrict__ x, const float* __restrict__ srcp,
                const float* __restrict__ micp, const float* __restrict__ jf,
                const float* __restrict__ jv, const float* __restrict__ pw,
                float* __restrict__ out, int T)
{
    const int b   = blockIdx.x;
    const int l   = threadIdx.x;
    const int wl  = l & 63;
    const int wid = l >> 6;

    __shared__ float  rows[NROW][RSTRA];
    __shared__ float  xl[PADX + TLEN + XPAD];
    __shared__ float  st[NN + 1][29];        // mic staging [row][step]
    __shared__ double nds[NN][3];
    __shared__ int    sshift[NROW];

    for (int i = l; i < NROW * RSTRA;       i += 256) (&rows[0][0])[i] = 0.f;
    for (int i = l; i < PADX + TLEN + XPAD; i += 256) xl[i] = 0.f;
    __syncthreads();
    for (int i = l; i < T; i += 256) xl[PADX + i] = x[i];

    const double room[3] = {4.0, 3.0, 2.5};
    double src[3] = {srcp[0], srcp[1], srcp[2]};
    double mic[3] = {micp[3*b+0], micp[3*b+1], micp[3*b+2]};

    if (l < NN) {
        int a = l >> 1;
        double w = (l & 1) ? room[a] : 0.0;
        double sa = (a == 0) ? src[0] : ((a == 1) ? src[1] : src[2]);
        double ma = (a == 0) ? mic[0] : ((a == 1) ? mic[1] : mic[2]);
        double ia = 2.0 * w - sa;
        double img0 = src[0], img1 = src[1], img2 = src[2];
        if (a == 0) img0 = ia; else if (a == 1) img1 = ia; else img2 = ia;
        double t = (w - ia) / (ma - ia);
        nds[l][0] = img0 + t * (mic[0] - img0);
        nds[l][1] = img1 + t * (mic[1] - img1);
        nds[l][2] = img2 + t * (mic[2] - img2);
    }
    __syncthreads();

    const double G = 343.0 / 16000.0;
    const int n  = (wl < 48) ? (wl >> 3) : 0;
    const int ir = wl & 7;
    const bool isline = (wl < 48) && (ir < 5);
    const bool ismic  = (wl < 48) && (ir == 5);
    const bool isdir  = (wl == 6);

    const int lineid = n * 5 + ir;                       // valid when isline
    #define PERMF(i) ((6*((i)+1) - ((i)%6) - 1) % NLn)
    const int srcl = PERMF(lineid % NLn);                // source line we read
    #undef PERMF
    const int ns = srcl / 5;                             // source line's node

    // own-node geometry (inj, micg, uu)
    double dx = nds[n][0] - src[0], dy = nds[n][1] - src[1], dz = nds[n][2] - src[2];
    double dsn = sqrt(dx*dx + dy*dy + dz*dz);
    dx = nds[n][0] - mic[0]; dy = nds[n][1] - mic[1]; dz = nds[n][2] - mic[2];
    double dnm = sqrt(dx*dx + dy*dy + dz*dz);
    dx = mic[0] - src[0]; dy = mic[1] - src[1]; dz = mic[2] - src[2];
    double dsm = sqrt(dx*dx + dy*dy + dz*dz);

    const int   Dsn  = (int)rint(dsn / G);
    const int   Dsm  = (int)rint(dsm / G);
    const float srcg = (float)(0.5 * G / dsn);
    const float micg = (float)(1.0 / (1.0 + dnm / dsn));
    const float dirg = (float)(1.0 / dsm);

    // delay of the row this lane READS
    int Dline;
    {
        int mm = srcl % 5;
        int m2 = mm + (mm >= ns ? 1 : 0);                // PAIRS of source line
        double ax = nds[ns][0] - nds[m2][0];
        double ay = nds[ns][1] - nds[m2][1];
        double az = nds[ns][2] - nds[m2][2];
        Dline = (int)rint(sqrt(ax*ax + ay*ay + az*az) / G);
    }
    const int Dmic = (int)rint(dnm / G);
    const int D = isline ? Dline : (ismic ? Dmic : 64);

    // injection (own node for lines; direct lane uses dsm path)
    float srcgl; int xoff;
    if (isline || ismic) { srcgl = srcg; xoff = PADX - Dsn; }
    else if (isdir)      { srcgl = dirg; xoff = PADX - Dsm; }
    else                 { srcgl = 0.f;  xoff = PADX; }

    // FIR coefficients: node of the row we read (source line's node / own node)
    const int nc = isline ? ns : n;
    const bool hasfir = isline || ismic;
    float c0,c1,c2,c3,c4,c5,c6,c7;
    {
        const float* f = jf + nc*(FIRN+1);
        c0 = hasfir ? f[7] : 0.f; c1 = hasfir ? f[6] : 0.f;
        c2 = hasfir ? f[5] : 0.f; c3 = hasfir ? f[4] : 0.f;
        c4 = hasfir ? f[3] : 0.f; c5 = hasfir ? f[2] : 0.f;
        c6 = hasfir ? f[1] : 0.f; c7 = hasfir ? f[0] : 0.f;
    }

    // butterfly weights and write-value constants
    const float uu = jv[n*5+0]*jv[n*5+0] + jv[n*5+1]*jv[n*5+1] + jv[n*5+2]*jv[n*5+2]
                   + jv[n*5+3]*jv[n*5+3] + jv[n*5+4]*jv[n*5+4];
    const float c2u = 2.0f / uu;
    const float vw = isline ? jv[n*5+ir] : 0.f;                  // v_j weight
    const float qw = isline ? micg * pw[n*5+ir] : 0.f;           // micg*q_j weight
    float Wa;
    if (isline) Wa = vw;
    else if (ismic) {
        Wa = micg * (jv[n*5+0]*pw[n*5+0] + jv[n*5+1]*pw[n*5+1] + jv[n*5+2]*pw[n*5+2]
                   + jv[n*5+3]*pw[n*5+3] + jv[n*5+4]*pw[n*5+4]);
    } else Wa = 0.f;

    // row ids
    const int rdrow = isline ? srcl : (ismic ? NLn + n : NROW - 1);
    const int wrrow = isline ? lineid : (ismic ? NLn + n : NROW - 1);
    const bool haswrite = isline || ismic;
    const bool hasstage = ismic || isdir;

    const int k0off = SPW * wid;                 // 0,7,14,21
    const int shift = isline ? 8 : 7;            // u window: k0-shift-D+j

    // ---- per-row bank rotation: reader bank == (reader lane & 31) ----
    // wave-0 reader of rdrow: bank(j=0,t=0) = (rdrow*RSTRA + s - shift - D) mod 32
    if (wid == 0) {
        if (isline || ismic) {
            int v = ((wl & 31) - rdrow * RSTRA + shift + D) % 32;
            sshift[rdrow] = (v + 32) % 32;
        }
        if (l == 0) {   // dummy row: steer pad broadcast to spare bank 6
            int v = (6 - (NROW-1) * RSTRA + 7 + 64) % 32;
            sshift[NROW-1] = (v + 32) % 32;
        }
    }
    __syncthreads();

    float* rdbase = &rows[rdrow][0] + sshift[rdrow];
    float* wrbase = &rows[wrrow][0] + sshift[wrrow];
    float* strow  = st[ismic ? n : 6];
    const float* xpc = xl + xoff;
    float* outp = out + b * T;

    // prefetch-unsafe: newest prefetched step may be written by OTHER lanes
    // during the overlapped batch.
    const bool needrr = (D < (42 - shift + k0off));

    int cur_off = ((k0off - shift - D) % LCAP + LCAP) % LCAP;
    int wp0 = 0;
    const int NB = (T + BATCH - 1) / BATCH;      // 143 for T=4000

    float u[NU], xq[SPW];
    // prologue: prefetch batch 0 (ring is zero-initialized)
    #pragma unroll
    for (int j = 0; j < NU; ++j) u[j] = rdbase[cur_off + j];
    #pragma unroll
    for (int i = 0; i < SPW; ++i) xq[i] = xpc[k0off + i];
    int nxt_off = cur_off + BATCH; if (nxt_off >= LCAP) nxt_off -= LCAP;

    for (int t = 0; t < NB; ++t) {
        // ---- re-read for prefetch-unsafe lanes (execz-skipped when none) ----
        if (needrr) {
            #pragma unroll
            for (int j = 0; j < NU; ++j) u[j] = rdbase[cur_off + j];
        }

        // ---- B: direct-form FIRs + injection -> p ----
        float fir[SPW], inj[SPW], p[SPW];
        #pragma unroll
        for (int i = 0; i < SPW; ++i) {
            float a = c7 * u[i];
            a = fmaf(c6, u[i+1], a); a = fmaf(c5, u[i+2], a);
            a = fmaf(c4, u[i+3], a); a = fmaf(c3, u[i+4], a);
            a = fmaf(c2, u[i+5], a); a = fmaf(c1, u[i+6], a);
            a = fmaf(c0, u[i+7], a);
            inj[i] = srcgl * xq[i];
            if (isdir) a = inj[i];               // direct path output
            fir[i] = a;
            p[i] = a + inj[i];
        }

        // ---- C: DPP butterflies -> A,B per group; write values ----
        float wv[SPW];
        #pragma unroll
        for (int i = 0; i < SPW; ++i) {
            float tv = vw * p[i];
            float tq = qw * p[i];
            tv = dpp_xor_add<0xB1>(tv); tq = dpp_xor_add<0xB1>(tq);  // xor1
            tv = dpp_xor_add<0x4E>(tv); tq = dpp_xor_add<0x4E>(tq);  // xor2
            float Av = tv + dpp_xquad(tv);                            // + other quad
            float Bv = tq + dpp_xquad(tq);
            float s  = Av * c2u;
            wv[i] = fmaf(s, Wa, -(ismic ? Bv : p[i]));
        }

        // ---- D: ring writes (+ mirror), mic staging ----
        if (haswrite) {
            #pragma unroll
            for (int i = 0; i < SPW; ++i) wrbase[wp0 + k0off + i] = wv[i];
        }
        if (wp0 == 0) {                          // uniform, 1 in 16 batches
            if (haswrite) {
                #pragma unroll
                for (int i = 0; i < SPW; ++i)
                    if (k0off + i < EXT) wrbase[LCAP + k0off + i] = wv[i];
            }
        }
        if (hasstage) {
            #pragma unroll
            for (int i = 0; i < SPW; ++i) strow[k0off + i] = fir[i];
        }

        // ---- prefetch batch t+1 (after ring writes: LDS aliasing orders; ----
        // ---- same-lane in-order covers own row; cross-lane via needrr) ----
        cur_off = nxt_off;
        #pragma unroll
        for (int j = 0; j < NU; ++j) u[j] = rdbase[cur_off + j];
        #pragma unroll
        for (int i = 0; i < SPW; ++i) xq[i] = xpc[(t+1)*BATCH + k0off + i];
        nxt_off += BATCH; if (nxt_off >= LCAP) nxt_off -= LCAP;

        // ---- F: coalesced output (lanes 0..6 sum 7 staged rows) ----
        if (wl < SPW) {
            int col  = k0off + wl;
            int gidx = t * BATCH + col;
            if (gidx < T) {
                float ssum = ((st[0][col] + st[1][col]) + (st[2][col] + st[3][col]))
                           + ((st[4][col] + st[5][col]) + st[6][col]);
                outp[gidx] = ssum;
            }
        }

        wp0 += BATCH; if (wp0 >= LCAP) wp0 -= LCAP;
        __syncthreads();                         // writes(t) before reads(t+1)
    }
}

extern "C" void kernel_launch(void* const* d_in, const int* in_sizes, int n_in,
                              void* d_out, int out_size, void* d_ws, size_t ws_size,
                              hipStream_t stream)
{
    const float* x    = (const float*)d_in[0];
    const float* srcp = (const float*)d_in[1];
    const float* micp = (const float*)d_in[2];
    const float* jf   = (const float*)d_in[3];
    const float* jv   = (const float*)d_in[4];
    const float* pw   = (const float*)d_in[5];
    float* out = (float*)d_out;

    int T  = in_sizes[0];
    if (T > TLEN) T = TLEN;
    int Bc = in_sizes[2] / 3;

    sdn_kernel<<<Bc, 256, 0, stream>>>(x, srcp, micp, jf, jv, pw, out, T);
}